// Round 3
// baseline (11649.852 us; speedup 1.0000x reference)
//
#include <hip/hip_runtime.h>
#include <hip/hip_bf16.h>

// Problem constants
#define Bz 16
#define Tz 32
#define Sz 128
#define TPz 4
#define Mz (Bz*Sz)          // 2048 rows
#define NSTEP (Tz-1)        // 31

typedef __bf16 bf16x8 __attribute__((ext_vector_type(8)));
typedef float  f32x4  __attribute__((ext_vector_type(4)));

// ---------------------------------------------------------------------------
// Weight prep (unchanged from passing round-2 version; fp32 in -> bf16 K-major)
//  WT_enc1 [1792][256]: [Wq|Wk|Wv|Wg_h]^T encoder (Wg rows 3:259)
//  WT_enc2 [1024][256]: enc Wg_ctx (rows 259:515)^T
//  WT_dec1 [1792][512]: k<256 = code -> (0 qkv, Wg rows 0:256); k>=256 = dh
//  WT_dec2 [1024][256]: dec Wg_ctx (rows 512:768)^T
//  WT_emb  [256][256]:  emb_W^T
// ---------------------------------------------------------------------------
__global__ __launch_bounds__(256) void prep_weights(
    const float* __restrict__ encWq, const float* __restrict__ encWk,
    const float* __restrict__ encWv, const float* __restrict__ encWg,
    const float* __restrict__ decWq, const float* __restrict__ decWk,
    const float* __restrict__ decWv, const float* __restrict__ decWg,
    const float* __restrict__ embW,
    __bf16* __restrict__ WT_enc1, __bf16* __restrict__ WT_enc2,
    __bf16* __restrict__ WT_dec1, __bf16* __restrict__ WT_dec2,
    __bf16* __restrict__ WT_emb)
{
    int id = blockIdx.x * 256 + threadIdx.x;
    if (id < 1792*256) {
        int n = id >> 8, k = id & 255;
        float v;
        if (n < 256)      v = encWq[k*256 + n];
        else if (n < 512) v = encWk[k*256 + (n-256)];
        else if (n < 768) v = encWv[k*256 + (n-512)];
        else              v = encWg[(3+k)*1024 + (n-768)];
        WT_enc1[id] = (__bf16)v; return;
    }
    id -= 1792*256;
    if (id < 1024*256) {
        int n = id >> 8, k = id & 255;
        WT_enc2[id] = (__bf16)encWg[(259+k)*1024 + n]; return;
    }
    id -= 1024*256;
    if (id < 1792*512) {
        int n = id >> 9, k = id & 511;
        float v;
        if (k < 256) {
            v = (n < 768) ? 0.f : decWg[k*1024 + (n-768)];
        } else {
            int k2 = k - 256;
            if (n < 256)      v = decWq[k2*256 + n];
            else if (n < 512) v = decWk[k2*256 + (n-256)];
            else if (n < 768) v = decWv[k2*256 + (n-512)];
            else              v = decWg[(256+k2)*1024 + (n-768)];
        }
        WT_dec1[id] = (__bf16)v; return;
    }
    id -= 1792*512;
    if (id < 1024*256) {
        int n = id >> 8, k = id & 255;
        WT_dec2[id] = (__bf16)decWg[(512+k)*1024 + n]; return;
    }
    id -= 1024*256;
    if (id < 256*256) {
        int n = id >> 8, k = id & 255;
        WT_emb[id] = (__bf16)embW[k*256 + n]; return;
    }
}

__device__ __forceinline__ float sigf(float x) { return 1.f/(1.f + __expf(-x)); }

// ---------------------------------------------------------------------------
// Attention over 4 spatial neighbors, per block = 32 rows of one batch.
// q from q_g (bf16), k/v from kvg (bf16, [row][k 0:256 | v 256:512]).
// ctx (bf16) -> ctxdst (LDS, row stride 520).
// wave w row = 4w+quad; lane lr covers channels lr*16..+16; head = lr>>1.
// ---------------------------------------------------------------------------
__device__ __forceinline__ void attn_phase(
    const __bf16* __restrict__ qg,   // + b*128*256
    const __bf16* __restrict__ kvg,  // + b*128*512
    __bf16* __restrict__ ctxdst,     // a4L + coff
    int s0, int tid)
{
    const int w = tid >> 6, lane = tid & 63, quad = lane >> 4, lr = lane & 15;
    const int row = 4*w + quad;          // 0..31 local
    const int s   = s0 + row;            // 0..127 in batch
    const int ch0 = lr*16;

    float q[16];
    {
        const bf16x8* qp = (const bf16x8*)(qg + (size_t)s*256 + ch0);
        bf16x8 q0 = qp[0], q1 = qp[1];
        #pragma unroll
        for (int i = 0; i < 8; ++i) { q[i] = (float)q0[i]; q[8+i] = (float)q1[i]; }
    }
    bf16x8 zv;
    #pragma unroll
    for (int i = 0; i < 8; ++i) zv[i] = (__bf16)0.f;

    const int offs[4] = {2, 1, -1, -2};
    float sc[4];
    bf16x8 v0[4], v1[4];
    #pragma unroll
    for (int n = 0; n < 4; ++n) {
        int s2 = s + offs[n];
        bool ok = ((unsigned)s2 < 128u);
        float p = 0.f;
        if (ok) {
            const bf16x8* kp = (const bf16x8*)(kvg + (size_t)s2*512 + ch0);
            bf16x8 k0 = kp[0], k1 = kp[1];
            const bf16x8* vp = (const bf16x8*)(kvg + (size_t)s2*512 + 256 + ch0);
            v0[n] = vp[0]; v1[n] = vp[1];
            #pragma unroll
            for (int i = 0; i < 8; ++i) p += q[i]*(float)k0[i] + q[8+i]*(float)k1[i];
        } else { v0[n] = zv; v1[n] = zv; }
        p += __shfl_xor(p, 1);                 // sum head pair (32 channels)
        sc[n] = ok ? p * 0.17677669529663687f : 0.f;   // 1/sqrt(32); pad => 0
    }
    float mx = fmaxf(fmaxf(sc[0], sc[1]), fmaxf(sc[2], sc[3]));
    float se = 0.f, aw[4];
    #pragma unroll
    for (int n = 0; n < 4; ++n) { aw[n] = __expf(sc[n] - mx); se += aw[n]; }
    float inv = 1.f/se;
    float cx[16];
    #pragma unroll
    for (int i = 0; i < 16; ++i) cx[i] = 0.f;
    #pragma unroll
    for (int n = 0; n < 4; ++n) {
        #pragma unroll
        for (int i = 0; i < 8; ++i) {
            cx[i]   += aw[n]*(float)v0[n][i];
            cx[8+i] += aw[n]*(float)v1[n][i];
        }
    }
    bf16x8 o0, o1;
    #pragma unroll
    for (int i = 0; i < 8; ++i) { o0[i] = (__bf16)(cx[i]*inv); o1[i] = (__bf16)(cx[8+i]*inv); }
    *(bf16x8*)(ctxdst + row*520 + ch0)     = o0;
    *(bf16x8*)(ctxdst + row*520 + ch0 + 8) = o1;
}

// ---------------------------------------------------------------------------
// Persistent scan kernel: 64 blocks (4 per batch, 32 rows each), 512 threads.
// ---------------------------------------------------------------------------
__global__ __launch_bounds__(512, 2) void scan_k(
    const float* __restrict__ input,
    const __bf16* __restrict__ WT1e, const __bf16* __restrict__ WT2e,
    const __bf16* __restrict__ WT1d, const __bf16* __restrict__ WT2d,
    const __bf16* __restrict__ WTemb,
    const float* __restrict__ encWg, const float* __restrict__ encbg,
    const float* __restrict__ decbg, const float* __restrict__ embb,
    const float* __restrict__ outW,  const float* __restrict__ outb,
    __bf16* __restrict__ q_g, __bf16* __restrict__ kve_g, __bf16* __restrict__ kvd_g,
    float* __restrict__ outbuf, unsigned* __restrict__ ctr,
    float* __restrict__ dout)
{
    const int tid  = threadIdx.x;
    const int w    = tid >> 6;
    const int lane = tid & 63;
    const int quad = lane >> 4;
    const int lr   = lane & 15;
    const int blk  = blockIdx.x;
    const int b    = blk >> 2;
    const int s0   = (blk & 3) << 5;      // 0,32,64,96
    const int gm   = b*Sz + s0;           // global row base

    __shared__ __bf16 ehbL[32*264];       // encoder h (bf16), stride 264
    __shared__ __bf16 a4L [32*520];       // [code|dh] / [ctx_e|ctx_d], stride 520
    __shared__ float  xL[32*4];
    __shared__ float  outredL[8*32];

    for (int i = tid; i < 32*264; i += 512) ehbL[i] = (__bf16)0.f;
    for (int i = tid; i < 32*520; i += 512) a4L[i]  = (__bf16)0.f;

    f32x4 z[2][4][2];                      // gate accs [tile][i,f,g,o][chunk]
    f32x4 ec[2][2], dh[2][2];              // persistent cell states (fp32)
    #pragma unroll
    for (int ti = 0; ti < 2; ++ti)
        #pragma unroll
        for (int c = 0; c < 2; ++c) {
            ec[ti][c] = f32x4{0.f,0.f,0.f,0.f};
            dh[ti][c] = f32x4{0.f,0.f,0.f,0.f};
        }
    __syncthreads();

    unsigned* cp = ctr + b*16;
    unsigned bar = 0;

#define GBAR() do {                                                            \
        __syncthreads();                                                       \
        ++bar;                                                                 \
        if (tid == 0) {                                                        \
            __threadfence();                                                   \
            atomicAdd(cp, 1u);                                                 \
            unsigned tgt = 4u*bar;                                             \
            while (__hip_atomic_load(cp, __ATOMIC_ACQUIRE,                     \
                                     __HIP_MEMORY_SCOPE_AGENT) < tgt)          \
                __builtin_amdgcn_s_sleep(2);                                   \
            __threadfence();                                                   \
        }                                                                      \
        __syncthreads();                                                       \
    } while (0)

    for (int t = 0; t < NSTEP; ++t) {
        // stage x(t) for own rows
        if (tid < 96) xL[(tid/3)*4 + (tid % 3)] =
            input[((size_t)(b*Tz + t)*Sz + s0)*3 + tid];

        // ---------------- E1: [q|k|v|gates_h] = ehb @ WT1e^T ----------------
        #pragma unroll
        for (int ti = 0; ti < 2; ++ti) {
            bf16x8 af[8];
            #pragma unroll
            for (int kk = 0; kk < 8; ++kk)
                af[kk] = *(const bf16x8*)&ehbL[(ti*16 + lr)*264 + kk*32 + quad*8];
            // q
            #pragma unroll
            for (int c = 0; c < 2; ++c) {
                int n0 = 32*w + 16*c;
                f32x4 acc = f32x4{0.f,0.f,0.f,0.f};
                const __bf16* bp = WT1e + (size_t)(n0 + lr)*256 + quad*8;
                #pragma unroll
                for (int kk = 0; kk < 8; ++kk)
                    acc = __builtin_amdgcn_mfma_f32_16x16x32_bf16(af[kk], *(const bf16x8*)(bp + kk*32), acc, 0,0,0);
                #pragma unroll
                for (int r = 0; r < 4; ++r)
                    q_g[(size_t)(gm + ti*16 + quad*4 + r)*256 + n0 + lr] = (__bf16)acc[r];
            }
            // k,v -> kve_g
            #pragma unroll
            for (int cc = 0; cc < 4; ++cc) {
                int n0 = 256 + (cc>>1)*256 + 32*w + 16*(cc&1);
                f32x4 acc = f32x4{0.f,0.f,0.f,0.f};
                const __bf16* bp = WT1e + (size_t)(n0 + lr)*256 + quad*8;
                #pragma unroll
                for (int kk = 0; kk < 8; ++kk)
                    acc = __builtin_amdgcn_mfma_f32_16x16x32_bf16(af[kk], *(const bf16x8*)(bp + kk*32), acc, 0,0,0);
                int col = n0 - 256;
                #pragma unroll
                for (int r = 0; r < 4; ++r)
                    kve_g[(size_t)(gm + ti*16 + quad*4 + r)*512 + col + lr] = (__bf16)acc[r];
            }
            // gates (h part) -> z
            #pragma unroll
            for (int g = 0; g < 4; ++g)
                #pragma unroll
                for (int c = 0; c < 2; ++c) {
                    int n0 = 768 + g*256 + 32*w + 16*c;
                    f32x4 acc = f32x4{0.f,0.f,0.f,0.f};
                    const __bf16* bp = WT1e + (size_t)(n0 + lr)*256 + quad*8;
                    #pragma unroll
                    for (int kk = 0; kk < 8; ++kk)
                        acc = __builtin_amdgcn_mfma_f32_16x16x32_bf16(af[kk], *(const bf16x8*)(bp + kk*32), acc, 0,0,0);
                    z[ti][g][c] = acc;
                }
        }
        GBAR();   // B1: kv halos published

        // ---------------- E attention -> ctx in a4L[0:256) ----------------
        attn_phase(q_g + (size_t)b*Sz*256, kve_g + (size_t)b*Sz*512, a4L, s0, tid);
        __syncthreads();

        // ---------------- E2: z += ctx @ WT2e ; enc LSTM ----------------
        #pragma unroll
        for (int ti = 0; ti < 2; ++ti) {
            bf16x8 af[8];
            #pragma unroll
            for (int kk = 0; kk < 8; ++kk)
                af[kk] = *(const bf16x8*)&a4L[(ti*16 + lr)*520 + kk*32 + quad*8];
            #pragma unroll
            for (int g = 0; g < 4; ++g)
                #pragma unroll
                for (int c = 0; c < 2; ++c) {
                    int n0 = g*256 + 32*w + 16*c;
                    const __bf16* bp = WT2e + (size_t)(n0 + lr)*256 + quad*8;
                    f32x4 acc = z[ti][g][c];
                    #pragma unroll
                    for (int kk = 0; kk < 8; ++kk)
                        acc = __builtin_amdgcn_mfma_f32_16x16x32_bf16(af[kk], *(const bf16x8*)(bp + kk*32), acc, 0,0,0);
                    z[ti][g][c] = acc;
                }
        }
        #pragma unroll
        for (int ti = 0; ti < 2; ++ti)
            #pragma unroll
            for (int c = 0; c < 2; ++c) {
                int ch = 32*w + 16*c + lr;
                float wx0[4], wx1[4], wx2[4], bgv[4];
                #pragma unroll
                for (int g = 0; g < 4; ++g) {
                    int cc = g*256 + ch;
                    wx0[g] = encWg[cc]; wx1[g] = encWg[1024+cc]; wx2[g] = encWg[2048+cc];
                    bgv[g] = encbg[cc];
                }
                #pragma unroll
                for (int r = 0; r < 4; ++r) {
                    int row = ti*16 + quad*4 + r;
                    float x0 = xL[row*4], x1 = xL[row*4+1], x2 = xL[row*4+2];
                    float vi = z[ti][0][c][r] + x0*wx0[0] + x1*wx1[0] + x2*wx2[0] + bgv[0];
                    float vf = z[ti][1][c][r] + x0*wx0[1] + x1*wx1[1] + x2*wx2[1] + bgv[1];
                    float vg = z[ti][2][c][r] + x0*wx0[2] + x1*wx1[2] + x2*wx2[2] + bgv[2];
                    float vo = z[ti][3][c][r] + x0*wx0[3] + x1*wx1[3] + x2*wx2[3] + bgv[3];
                    float cn = sigf(vf)*ec[ti][c][r] + sigf(vi)*tanhf(vg);
                    ec[ti][c][r] = cn;
                    ehbL[row*264 + ch] = (__bf16)(sigf(vo)*tanhf(cn));
                }
            }
        __syncthreads();

        // ---------------- E3: code = sig(ehb@embW+b) -> a4L[0:256) ----------------
        #pragma unroll
        for (int ti = 0; ti < 2; ++ti) {
            bf16x8 af[8];
            #pragma unroll
            for (int kk = 0; kk < 8; ++kk)
                af[kk] = *(const bf16x8*)&ehbL[(ti*16 + lr)*264 + kk*32 + quad*8];
            #pragma unroll
            for (int c = 0; c < 2; ++c) {
                int n0 = 32*w + 16*c;
                const __bf16* bp = WTemb + (size_t)(n0 + lr)*256 + quad*8;
                f32x4 acc = f32x4{0.f,0.f,0.f,0.f};
                #pragma unroll
                for (int kk = 0; kk < 8; ++kk)
                    acc = __builtin_amdgcn_mfma_f32_16x16x32_bf16(af[kk], *(const bf16x8*)(bp + kk*32), acc, 0,0,0);
                float bb = embb[n0 + lr];
                #pragma unroll
                for (int r = 0; r < 4; ++r)
                    a4L[(ti*16 + quad*4 + r)*520 + n0 + lr] = (__bf16)sigf(acc[r] + bb);
            }
        }
        __syncthreads();

        // ---------------- D1: [q|k|v|gates] = [code|dh] @ WT1d^T (K=512) ----------------
        #pragma unroll
        for (int ti = 0; ti < 2; ++ti) {
            f32x4 qa[2], kva[4];
            #pragma unroll
            for (int c = 0; c < 2; ++c) qa[c] = f32x4{0.f,0.f,0.f,0.f};
            #pragma unroll
            for (int cc = 0; cc < 4; ++cc) kva[cc] = f32x4{0.f,0.f,0.f,0.f};
            #pragma unroll
            for (int g = 0; g < 4; ++g)
                #pragma unroll
                for (int c = 0; c < 2; ++c) z[ti][g][c] = f32x4{0.f,0.f,0.f,0.f};
            #pragma unroll
            for (int half = 0; half < 2; ++half) {
                bf16x8 af[8];
                #pragma unroll
                for (int kk = 0; kk < 8; ++kk)
                    af[kk] = *(const bf16x8*)&a4L[(ti*16 + lr)*520 + half*256 + kk*32 + quad*8];
                #pragma unroll
                for (int c = 0; c < 2; ++c) {
                    int n0 = 32*w + 16*c;
                    const __bf16* bp = WT1d + (size_t)(n0 + lr)*512 + half*256 + quad*8;
                    f32x4 acc = qa[c];
                    #pragma unroll
                    for (int kk = 0; kk < 8; ++kk)
                        acc = __builtin_amdgcn_mfma_f32_16x16x32_bf16(af[kk], *(const bf16x8*)(bp + kk*32), acc, 0,0,0);
                    qa[c] = acc;
                }
                #pragma unroll
                for (int cc = 0; cc < 4; ++cc) {
                    int n0 = 256 + (cc>>1)*256 + 32*w + 16*(cc&1);
                    const __bf16* bp = WT1d + (size_t)(n0 + lr)*512 + half*256 + quad*8;
                    f32x4 acc = kva[cc];
                    #pragma unroll
                    for (int kk = 0; kk < 8; ++kk)
                        acc = __builtin_amdgcn_mfma_f32_16x16x32_bf16(af[kk], *(const bf16x8*)(bp + kk*32), acc, 0,0,0);
                    kva[cc] = acc;
                }
                #pragma unroll
                for (int g = 0; g < 4; ++g)
                    #pragma unroll
                    for (int c = 0; c < 2; ++c) {
                        int n0 = 768 + g*256 + 32*w + 16*c;
                        const __bf16* bp = WT1d + (size_t)(n0 + lr)*512 + half*256 + quad*8;
                        f32x4 acc = z[ti][g][c];
                        #pragma unroll
                        for (int kk = 0; kk < 8; ++kk)
                            acc = __builtin_amdgcn_mfma_f32_16x16x32_bf16(af[kk], *(const bf16x8*)(bp + kk*32), acc, 0,0,0);
                        z[ti][g][c] = acc;
                    }
            }
            #pragma unroll
            for (int c = 0; c < 2; ++c) {
                int n0 = 32*w + 16*c;
                #pragma unroll
                for (int r = 0; r < 4; ++r)
                    q_g[(size_t)(gm + ti*16 + quad*4 + r)*256 + n0 + lr] = (__bf16)qa[c][r];
            }
            #pragma unroll
            for (int cc = 0; cc < 4; ++cc) {
                int n0 = 256 + (cc>>1)*256 + 32*w + 16*(cc&1);
                int col = n0 - 256;
                #pragma unroll
                for (int r = 0; r < 4; ++r)
                    kvd_g[(size_t)(gm + ti*16 + quad*4 + r)*512 + col + lr] = (__bf16)kva[cc][r];
            }
        }
        GBAR();   // B2: dec kv halos published

        // ---------------- D attention -> ctx in a4L[256:512) ----------------
        attn_phase(q_g + (size_t)b*Sz*256, kvd_g + (size_t)b*Sz*512, a4L + 256, s0, tid);
        __syncthreads();

        // ---------------- D2: z += ctx @ WT2d ----------------
        #pragma unroll
        for (int ti = 0; ti < 2; ++ti) {
            bf16x8 af[8];
            #pragma unroll
            for (int kk = 0; kk < 8; ++kk)
                af[kk] = *(const bf16x8*)&a4L[(ti*16 + lr)*520 + 256 + kk*32 + quad*8];
            #pragma unroll
            for (int g = 0; g < 4; ++g)
                #pragma unroll
                for (int c = 0; c < 2; ++c) {
                    int n0 = g*256 + 32*w + 16*c;
                    const __bf16* bp = WT2d + (size_t)(n0 + lr)*256 + quad*8;
                    f32x4 acc = z[ti][g][c];
                    #pragma unroll
                    for (int kk = 0; kk < 8; ++kk)
                        acc = __builtin_amdgcn_mfma_f32_16x16x32_bf16(af[kk], *(const bf16x8*)(bp + kk*32), acc, 0,0,0);
                    z[ti][g][c] = acc;
                }
        }
        __syncthreads();   // all ctx reads done before dh overwrites region

        // dec LSTM (c := dh(t-1)) + out projection
        {
            f32x4 p[2];
            p[0] = f32x4{0.f,0.f,0.f,0.f}; p[1] = f32x4{0.f,0.f,0.f,0.f};
            #pragma unroll
            for (int ti = 0; ti < 2; ++ti)
                #pragma unroll
                for (int c = 0; c < 2; ++c) {
                    int ch = 32*w + 16*c + lr;
                    float bgv[4];
                    #pragma unroll
                    for (int g = 0; g < 4; ++g) bgv[g] = decbg[g*256 + ch];
                    float ow = outW[ch];
                    #pragma unroll
                    for (int r = 0; r < 4; ++r) {
                        float vi = z[ti][0][c][r] + bgv[0];
                        float vf = z[ti][1][c][r] + bgv[1];
                        float vg = z[ti][2][c][r] + bgv[2];
                        float vo = z[ti][3][c][r] + bgv[3];
                        float cn = sigf(vf)*dh[ti][c][r] + sigf(vi)*tanhf(vg);
                        float hn = sigf(vo)*tanhf(cn);
                        dh[ti][c][r] = hn;
                        a4L[(ti*16 + quad*4 + r)*520 + 256 + ch] = (__bf16)hn;
                        p[ti][r] += hn * ow;
                    }
                }
            #pragma unroll
            for (int m = 1; m < 16; m <<= 1)
                #pragma unroll
                for (int ti = 0; ti < 2; ++ti)
                    #pragma unroll
                    for (int r = 0; r < 4; ++r)
                        p[ti][r] += __shfl_xor(p[ti][r], m);
            if (lr == 0) {
                #pragma unroll
                for (int ti = 0; ti < 2; ++ti)
                    #pragma unroll
                    for (int r = 0; r < 4; ++r)
                        outredL[w*32 + ti*16 + quad*4 + r] = p[ti][r];
            }
        }
        __syncthreads();
        if (tid < 32) {
            float s = 0.f;
            #pragma unroll
            for (int ww = 0; ww < 8; ++ww) s += outredL[ww*32 + tid];
            outbuf[t*Mz + gm + tid] = s;
        }
    }

    GBAR();   // final: all outbuf visible within batch

    // ---------------- assemble ----------------
    const float ob = outb[0];
    for (int ii = tid; ii < 27*32; ii += 512) {
        int i = ii >> 5, r = ii & 31, tt = i + TPz, s = s0 + r;
        float o  = outbuf[tt*Mz + b*Sz + s] + ob;
        float In = (s == 0) ? input[((size_t)(b*Tz + tt + 1)*Sz)*3 + 1]
                            : outbuf[tt*Mz + b*Sz + s - 1] + ob;
        float num = input[((size_t)(b*Tz + tt)*Sz + s)*3 + 2] + In - o;
        size_t base = ((size_t)(b*27 + i)*Sz + s)*3;
        dout[base]   = o;
        dout[base+1] = In;
        dout[base+2] = num;
    }
#undef GBAR
}

// ---------------------------------------------------------------------------
extern "C" void kernel_launch(void* const* d_in, const int* in_sizes, int n_in,
                              void* d_out, int out_size, void* d_ws, size_t ws_size,
                              hipStream_t stream)
{
    const float* input = (const float*)d_in[0];
    const float* encWq = (const float*)d_in[1];
    const float* encWk = (const float*)d_in[2];
    const float* encWv = (const float*)d_in[3];
    const float* encWg = (const float*)d_in[4];
    const float* encbg = (const float*)d_in[5];
    const float* decWq = (const float*)d_in[6];
    const float* decWk = (const float*)d_in[7];
    const float* decWv = (const float*)d_in[8];
    const float* decWg = (const float*)d_in[9];
    const float* decbg = (const float*)d_in[10];
    const float* embW  = (const float*)d_in[11];
    const float* embb  = (const float*)d_in[12];
    const float* outW  = (const float*)d_in[13];
    const float* outb  = (const float*)d_in[14];

    char* ws = (char*)d_ws;
    size_t off = 0;
    auto alloc = [&](size_t bytes) -> void* {
        void* p = ws + off;
        off += (bytes + 255) & ~(size_t)255;
        return p;
    };
    __bf16* WT_enc1 = (__bf16*)alloc((size_t)1792*256*2);
    __bf16* WT_enc2 = (__bf16*)alloc((size_t)1024*256*2);
    __bf16* WT_dec1 = (__bf16*)alloc((size_t)1792*512*2);
    __bf16* WT_dec2 = (__bf16*)alloc((size_t)1024*256*2);
    __bf16* WT_emb  = (__bf16*)alloc((size_t)256*256*2);
    __bf16* q_g     = (__bf16*)alloc((size_t)Mz*256*2);
    __bf16* kve_g   = (__bf16*)alloc((size_t)Mz*512*2);
    __bf16* kvd_g   = (__bf16*)alloc((size_t)Mz*512*2);
    float*  outbuf  = (float*) alloc((size_t)NSTEP*Mz*4);
    unsigned* ctr   = (unsigned*)alloc(1024);

    hipMemsetAsync(ctr, 0, 1024, stream);
    prep_weights<<<7680, 256, 0, stream>>>(encWq, encWk, encWv, encWg,
                                           decWq, decWk, decWv, decWg, embW,
                                           WT_enc1, WT_enc2, WT_dec1, WT_dec2, WT_emb);
    scan_k<<<64, 512, 0, stream>>>(input,
                                   WT_enc1, WT_enc2, WT_dec1, WT_dec2, WT_emb,
                                   encWg, encbg, decbg, embb, outW, outb,
                                   q_g, kve_g, kvd_g, outbuf, ctr, (float*)d_out);
}

// Round 4
// 5247.390 us; speedup vs baseline: 2.2201x; 2.2201x over previous
//
#include <hip/hip_runtime.h>
#include <hip/hip_bf16.h>

// Problem constants
#define Bz 16
#define Tz 32
#define Sz 128
#define TPz 4
#define Mz (Bz*Sz)          // 2048 rows
#define NSTEP (Tz-1)        // 31

typedef __bf16 bf16x8 __attribute__((ext_vector_type(8)));
typedef __bf16 bf16x4 __attribute__((ext_vector_type(4)));
typedef float  f32x4  __attribute__((ext_vector_type(4)));

__device__ __forceinline__ float sigf(float x) { return 1.f/(1.f + __expf(-x)); }

// ---------------------------------------------------------------------------
// Weight prep (fp32 in -> bf16, K-major / packed):
//  Wqkv_e [768][256] : enc [Wq|Wk|Wv]^T
//  Wg_e  [1024][512] : enc gates, K=[h(256)|ctx(256)], N gate-interleaved:
//                      n: half=n>>9, idx=n&511, Nt=idx>>4, g=Nt&3, cht=Nt>>2,
//                      lr=idx&15, ch=half*128+cht*16+lr, src col=g*256+ch
//  Wk3   [1024][256] : [embW | dec Wq | dec Wk | dec Wv]^T (all K=256)
//  Wg_d  [1024][768] : dec gates, K=[code|dh|ctx], same N packing
// ---------------------------------------------------------------------------
__global__ __launch_bounds__(256) void prep2(
    const float* __restrict__ encWq, const float* __restrict__ encWk,
    const float* __restrict__ encWv, const float* __restrict__ encWg,
    const float* __restrict__ decWq, const float* __restrict__ decWk,
    const float* __restrict__ decWv, const float* __restrict__ decWg,
    const float* __restrict__ embW,
    __bf16* __restrict__ Wqkv_e, __bf16* __restrict__ Wg_e,
    __bf16* __restrict__ Wk3,    __bf16* __restrict__ Wg_d)
{
    int id = blockIdx.x * 256 + threadIdx.x;
    if (id < 768*256) {
        int n = id >> 8, k = id & 255;
        float v = (n < 256) ? encWq[k*256 + n]
                : (n < 512) ? encWk[k*256 + (n-256)]
                            : encWv[k*256 + (n-512)];
        Wqkv_e[id] = (__bf16)v; return;
    }
    id -= 768*256;
    if (id < 1024*512) {
        int n = id >> 9, k = id & 511;
        int half = n >> 9, idx = n & 511;
        int Nt = idx >> 4, g = Nt & 3, cht = Nt >> 2, lr = idx & 15;
        int ch = half*128 + cht*16 + lr;
        int sc = g*256 + ch;
        float v = (k < 256) ? encWg[(3+k)*1024 + sc]
                            : encWg[(259+(k-256))*1024 + sc];
        Wg_e[(size_t)n*512 + k] = (__bf16)v; return;
    }
    id -= 1024*512;
    if (id < 1024*256) {
        int n = id >> 8, k = id & 255;
        float v = (n < 256) ? embW[k*256 + n]
                : (n < 512) ? decWq[k*256 + (n-256)]
                : (n < 768) ? decWk[k*256 + (n-512)]
                            : decWv[k*256 + (n-768)];
        Wk3[id] = (__bf16)v; return;
    }
    id -= 1024*256;
    if (id < 1024*768) {
        int n = id / 768, k = id % 768;
        int half = n >> 9, idx = n & 511;
        int Nt = idx >> 4, g = Nt & 3, cht = Nt >> 2, lr = idx & 15;
        int ch = half*128 + cht*16 + lr;
        int sc = g*256 + ch;
        Wg_d[(size_t)n*768 + k] = (__bf16)decWg[k*1024 + sc]; return;
    }
}

// ---------------------------------------------------------------------------
// GEMM 128x128 tile, K=256, BK=32 (verified round-2 core), A has lda (bf16).
// EPI 0 (enc qkv, N=768):  col<256 -> q_g ; col>=256 -> kv_g[col-256]
// EPI 1 (emb + dec qkv, N=1024): blockIdx.y<2: A+0 (ehb), sigmoid -> codeb
//        y in {2,3}: A+256 (dh) -> q_g[col-256]; y>=4: A+256 -> kv_g[col-512]
// ---------------------------------------------------------------------------
template<int EPI>
__global__ __launch_bounds__(256, 2) void gemm_qkv(
    const __bf16* __restrict__ Abase, int lda,
    const __bf16* __restrict__ BT, int K,
    __bf16* __restrict__ q_g, __bf16* __restrict__ kv_g,
    __bf16* __restrict__ codeb, const float* __restrict__ embb)
{
    __shared__ __attribute__((aligned(16))) __bf16 As[128*32];
    __shared__ __attribute__((aligned(16))) __bf16 Bs[128*32];
    const int tid  = threadIdx.x;
    const int m0   = blockIdx.x << 7;
    const int n0   = blockIdx.y << 7;
    const int lane = tid & 63;
    const int w    = tid >> 6;
    const int quad = lane >> 4, lr = lane & 15;
    const int wm   = (w >> 1) << 6, wn = (w & 1) << 6;

    const __bf16* A = Abase + ((EPI == 1 && blockIdx.y >= 2) ? 256 : 0);

    f32x4 acc[4][4];
    #pragma unroll
    for (int i = 0; i < 4; ++i)
        #pragma unroll
        for (int j = 0; j < 4; ++j) acc[i][j] = f32x4{0.f,0.f,0.f,0.f};

    const int r0 = tid >> 2;
    const int c0 = (tid & 3) << 3;
    const __bf16* gA0 = A  + (size_t)(m0 + r0)      * lda + c0;
    const __bf16* gA1 = A  + (size_t)(m0 + r0 + 64) * lda + c0;
    const __bf16* gB0 = BT + (size_t)(n0 + r0)      * K   + c0;
    const __bf16* gB1 = BT + (size_t)(n0 + r0 + 64) * K   + c0;

    for (int k0 = 0; k0 < K; k0 += 32) {
        uint4 a0 = *(const uint4*)(gA0 + k0);
        uint4 a1 = *(const uint4*)(gA1 + k0);
        uint4 b0 = *(const uint4*)(gB0 + k0);
        uint4 b1 = *(const uint4*)(gB1 + k0);
        __syncthreads();
        ((uint4*)As)[tid]       = a0;
        ((uint4*)As)[tid + 256] = a1;
        ((uint4*)Bs)[tid]       = b0;
        ((uint4*)Bs)[tid + 256] = b1;
        __syncthreads();
        bf16x8 af[4], bfr[4];
        #pragma unroll
        for (int i = 0; i < 4; ++i)
            af[i]  = *(const bf16x8*)&As[(wm + i*16 + lr)*32 + quad*8];
        #pragma unroll
        for (int i = 0; i < 4; ++i)
            bfr[i] = *(const bf16x8*)&Bs[(wn + i*16 + lr)*32 + quad*8];
        #pragma unroll
        for (int mi = 0; mi < 4; ++mi)
            #pragma unroll
            for (int ni = 0; ni < 4; ++ni)
                acc[mi][ni] = __builtin_amdgcn_mfma_f32_16x16x32_bf16(
                    af[mi], bfr[ni], acc[mi][ni], 0, 0, 0);
    }

    #pragma unroll
    for (int mi = 0; mi < 4; ++mi) {
        #pragma unroll
        for (int ni = 0; ni < 4; ++ni) {
            const int col = n0 + wn + ni*16 + lr;
            #pragma unroll
            for (int r = 0; r < 4; ++r) {
                const int row = m0 + wm + mi*16 + quad*4 + r;
                float v = acc[mi][ni][r];
                if (EPI == 0) {
                    if (col < 256) q_g[(size_t)row*256 + col] = (__bf16)v;
                    else           kv_g[(size_t)row*512 + (col-256)] = (__bf16)v;
                } else {
                    if (col < 256)
                        codeb[(size_t)row*256 + col] = (__bf16)sigf(v + embb[col]);
                    else if (col < 512)
                        q_g[(size_t)row*256 + (col-256)] = (__bf16)v;
                    else
                        kv_g[(size_t)row*512 + (col-512)] = (__bf16)v;
                }
            }
        }
    }
}

// ---------------------------------------------------------------------------
// Shared attention phase: 8 waves x 16 rows = 128 rows of batch b.
// head = lane>>3 (8 heads), ch = head*32 + (lane&7)*4 (4 consecutive ch).
// Writes full 256-ch ctx (bf16) into ctxL (row stride 264).
// ---------------------------------------------------------------------------
__device__ __forceinline__ void attn_dev(
    const __bf16* __restrict__ q_g, const __bf16* __restrict__ kv_g,
    int gb, int w, int lane, __bf16* __restrict__ ctxL)
{
    const int ch = (lane >> 3)*32 + (lane & 7)*4;
    const int offs[4] = {2, 1, -1, -2};
    for (int i = 0; i < 16; ++i) {
        const int s = (w << 4) + i;
        bf16x4 q4 = *(const bf16x4*)&q_g[(size_t)(gb + s)*256 + ch];
        const float q0 = (float)q4[0], q1 = (float)q4[1],
                    q2 = (float)q4[2], q3 = (float)q4[3];
        float sc[4]; bf16x4 vv[4];
        #pragma unroll
        for (int n = 0; n < 4; ++n) {
            const int s2 = s + offs[n];
            const bool ok = ((unsigned)s2 < 128u);
            float p = 0.f;
            if (ok) {
                bf16x4 k4 = *(const bf16x4*)&kv_g[(size_t)(gb + s2)*512 + ch];
                vv[n]     = *(const bf16x4*)&kv_g[(size_t)(gb + s2)*512 + 256 + ch];
                p = q0*(float)k4[0] + q1*(float)k4[1] + q2*(float)k4[2] + q3*(float)k4[3];
            } else {
                vv[n][0] = vv[n][1] = vv[n][2] = vv[n][3] = (__bf16)0.f;
            }
            p += __shfl_xor(p, 1); p += __shfl_xor(p, 2); p += __shfl_xor(p, 4);
            sc[n] = ok ? p * 0.17677669529663687f : 0.f;
        }
        const float mx = fmaxf(fmaxf(sc[0], sc[1]), fmaxf(sc[2], sc[3]));
        float se = 0.f, aw[4];
        #pragma unroll
        for (int n = 0; n < 4; ++n) { aw[n] = __expf(sc[n] - mx); se += aw[n]; }
        const float inv = 1.f / se;
        float c0 = 0.f, c1 = 0.f, c2 = 0.f, c3 = 0.f;
        #pragma unroll
        for (int n = 0; n < 4; ++n) {
            c0 += aw[n]*(float)vv[n][0]; c1 += aw[n]*(float)vv[n][1];
            c2 += aw[n]*(float)vv[n][2]; c3 += aw[n]*(float)vv[n][3];
        }
        bf16x4 o;
        o[0] = (__bf16)(c0*inv); o[1] = (__bf16)(c1*inv);
        o[2] = (__bf16)(c2*inv); o[3] = (__bf16)(c3*inv);
        *(bf16x4*)&ctxL[s*264 + ch] = o;
    }
}

// ---------------------------------------------------------------------------
// F_enc: block = (batch, ch-half). attn -> ctxL; gates GEMM (K=512: ehb|ctx);
// LSTM (x-part folded) -> ec (fp32 global), ehb_t -> Xq[,0:256].
// ---------------------------------------------------------------------------
__global__ __launch_bounds__(512, 2) void f_enc(
    const float* __restrict__ input, int t,
    const __bf16* __restrict__ Xp, __bf16* __restrict__ Xq,
    const __bf16* __restrict__ q_g, const __bf16* __restrict__ kv_g,
    const __bf16* __restrict__ Wg,
    const float* __restrict__ encWg, const float* __restrict__ encbg,
    float* __restrict__ ec)
{
    __shared__ __attribute__((aligned(16))) __bf16 ehbL[128*264];
    __shared__ __attribute__((aligned(16))) __bf16 ctxL[128*264];
    __shared__ float xL[128*3];

    const int tid  = threadIdx.x;
    const int w    = tid >> 6;
    const int lane = tid & 63;
    const int quad = lane >> 4, lr = lane & 15;
    const int b    = blockIdx.x >> 1, half = blockIdx.x & 1;
    const int gb   = b * 128;

    // stage ehb_{t-1} (Xp[,0:256], lda 512) -> LDS
    {
        const int row = tid >> 2, seg = tid & 3;
        const __bf16* src = Xp + (size_t)(gb + row)*512 + seg*64;
        __bf16* dst = ehbL + row*264 + seg*64;
        #pragma unroll
        for (int j = 0; j < 8; ++j)
            *(bf16x8*)(dst + j*8) = *(const bf16x8*)(src + j*8);
    }
    if (tid < 384) xL[tid] = input[((size_t)(b*Tz + t)*Sz)*3 + tid];

    attn_dev(q_g, kv_g, gb, w, lane, ctxL);
    __syncthreads();

    // per-lane LSTM constants for ch
    const int ch = half*128 + w*16 + lr;
    float wx0[4], wx1[4], wx2[4], bgv[4];
    #pragma unroll
    for (int g = 0; g < 4; ++g) {
        const int c = g*256 + ch;
        wx0[g] = encWg[c]; wx1[g] = encWg[1024 + c]; wx2[g] = encWg[2048 + c];
        bgv[g] = encbg[c];
    }

    // gates GEMM: 8 Mtiles x 4 gate-cols, K=512
    f32x4 acc[8][4];
    #pragma unroll
    for (int m = 0; m < 8; ++m)
        #pragma unroll
        for (int g = 0; g < 4; ++g) acc[m][g] = f32x4{0.f,0.f,0.f,0.f};

    const size_t brow = (size_t)(half*512 + w*64 + lr)*512;
    for (int kk = 0; kk < 16; ++kk) {
        bf16x8 bf[4];
        #pragma unroll
        for (int g = 0; g < 4; ++g)
            bf[g] = *(const bf16x8*)&Wg[brow + (size_t)g*16*512 + kk*32 + quad*8];
        const __bf16* Asrc = (kk < 8) ? (ehbL + kk*32) : (ctxL + (kk-8)*32);
        bf16x8 af[8];
        #pragma unroll
        for (int m = 0; m < 8; ++m)
            af[m] = *(const bf16x8*)&Asrc[(m*16 + lr)*264 + quad*8];
        #pragma unroll
        for (int m = 0; m < 8; ++m)
            #pragma unroll
            for (int g = 0; g < 4; ++g)
                acc[m][g] = __builtin_amdgcn_mfma_f32_16x16x32_bf16(
                    af[m], bf[g], acc[m][g], 0, 0, 0);
    }

    // LSTM epilogue
    #pragma unroll
    for (int m = 0; m < 8; ++m) {
        #pragma unroll
        for (int r = 0; r < 4; ++r) {
            const int row = m*16 + quad*4 + r;
            const float x0 = xL[row*3], x1 = xL[row*3+1], x2 = xL[row*3+2];
            const float zi = acc[m][0][r] + x0*wx0[0] + x1*wx1[0] + x2*wx2[0] + bgv[0];
            const float zf = acc[m][1][r] + x0*wx0[1] + x1*wx1[1] + x2*wx2[1] + bgv[1];
            const float zg = acc[m][2][r] + x0*wx0[2] + x1*wx1[2] + x2*wx2[2] + bgv[2];
            const float zo = acc[m][3][r] + x0*wx0[3] + x1*wx1[3] + x2*wx2[3] + bgv[3];
            const size_t ei = (size_t)(gb + row)*256 + ch;
            const float cn = sigf(zf)*ec[ei] + sigf(zi)*tanhf(zg);
            ec[ei] = cn;
            Xq[(size_t)(gb + row)*512 + ch] = (__bf16)(sigf(zo)*tanhf(cn));
        }
    }
}

// ---------------------------------------------------------------------------
// F_dec: attn -> ctxL; gates GEMM (K=768: code|dh|ctx); LSTM (c = dh_{t-1});
// dh_t -> Xp[,256:512]; out-projection partial -> atomicAdd outbuf.
// ---------------------------------------------------------------------------
__global__ __launch_bounds__(512, 2) void f_dec(
    const __bf16* __restrict__ Xq, __bf16* __restrict__ Xp,
    const __bf16* __restrict__ q_g, const __bf16* __restrict__ kv_g,
    const __bf16* __restrict__ codeb, const __bf16* __restrict__ Wg,
    const float* __restrict__ decbg, const float* __restrict__ outW,
    float* __restrict__ outbuf)
{
    __shared__ __attribute__((aligned(16))) __bf16 dhL[128*264];
    __shared__ __attribute__((aligned(16))) __bf16 ctxL[128*264];
    __shared__ float outredL[128*8];

    const int tid  = threadIdx.x;
    const int w    = tid >> 6;
    const int lane = tid & 63;
    const int quad = lane >> 4, lr = lane & 15;
    const int b    = blockIdx.x >> 1, half = blockIdx.x & 1;
    const int gb   = b * 128;

    // stage dh_{t-1} (Xq[,256:512]) -> LDS
    {
        const int row = tid >> 2, seg = tid & 3;
        const __bf16* src = Xq + (size_t)(gb + row)*512 + 256 + seg*64;
        __bf16* dst = dhL + row*264 + seg*64;
        #pragma unroll
        for (int j = 0; j < 8; ++j)
            *(bf16x8*)(dst + j*8) = *(const bf16x8*)(src + j*8);
    }

    attn_dev(q_g, kv_g, gb, w, lane, ctxL);
    __syncthreads();

    const int ch = half*128 + w*16 + lr;
    float bgv[4];
    #pragma unroll
    for (int g = 0; g < 4; ++g) bgv[g] = decbg[g*256 + ch];
    const float ow = outW[ch];

    f32x4 acc[8][4];
    #pragma unroll
    for (int m = 0; m < 8; ++m)
        #pragma unroll
        for (int g = 0; g < 4; ++g) acc[m][g] = f32x4{0.f,0.f,0.f,0.f};

    const size_t brow = (size_t)(half*512 + w*64 + lr)*768;
    for (int kk = 0; kk < 24; ++kk) {
        bf16x8 bf[4];
        #pragma unroll
        for (int g = 0; g < 4; ++g)
            bf[g] = *(const bf16x8*)&Wg[brow + (size_t)g*16*768 + kk*32 + quad*8];
        bf16x8 af[8];
        if (kk < 8) {
            #pragma unroll
            for (int m = 0; m < 8; ++m)
                af[m] = *(const bf16x8*)&codeb[(size_t)(gb + m*16 + lr)*256 + kk*32 + quad*8];
        } else {
            const __bf16* Asrc = (kk < 16) ? (dhL + (kk-8)*32) : (ctxL + (kk-16)*32);
            #pragma unroll
            for (int m = 0; m < 8; ++m)
                af[m] = *(const bf16x8*)&Asrc[(m*16 + lr)*264 + quad*8];
        }
        #pragma unroll
        for (int m = 0; m < 8; ++m)
            #pragma unroll
            for (int g = 0; g < 4; ++g)
                acc[m][g] = __builtin_amdgcn_mfma_f32_16x16x32_bf16(
                    af[m], bf[g], acc[m][g], 0, 0, 0);
    }

    // LSTM + out projection
    #pragma unroll
    for (int m = 0; m < 8; ++m) {
        #pragma unroll
        for (int r = 0; r < 4; ++r) {
            const int row = m*16 + quad*4 + r;
            const float zi = acc[m][0][r] + bgv[0];
            const float zf = acc[m][1][r] + bgv[1];
            const float zg = acc[m][2][r] + bgv[2];
            const float zo = acc[m][3][r] + bgv[3];
            const float c_old = (float)dhL[row*264 + ch];
            const float cn = sigf(zf)*c_old + sigf(zi)*tanhf(zg);
            const float h  = sigf(zo)*tanhf(cn);
            Xp[(size_t)(gb + row)*512 + 256 + ch] = (__bf16)h;
            float pv = h * ow;
            pv += __shfl_xor(pv, 1); pv += __shfl_xor(pv, 2);
            pv += __shfl_xor(pv, 4); pv += __shfl_xor(pv, 8);
            if (lr == 0) outredL[row*8 + w] = pv;
        }
    }
    __syncthreads();
    if (tid < 128) {
        float s = 0.f;
        #pragma unroll
        for (int ww = 0; ww < 8; ++ww) s += outredL[tid*8 + ww];
        atomicAdd(&outbuf[gb + tid], s);
    }
}

// ---------------------------------------------------------------------------
// Final assembly: out / In / num for scan steps t in [TP, T-2], fp32 output.
// ---------------------------------------------------------------------------
__global__ __launch_bounds__(256) void assemble_k(
    const float* __restrict__ outbuf, const float* __restrict__ input,
    const float* __restrict__ outb, float* __restrict__ out)
{
    const int idx = blockIdx.x*256 + threadIdx.x;
    const int NT = NSTEP - TPz;                 // 27
    if (idx >= Bz*NT*Sz) return;
    const int s  = idx & 127;
    const int bi = idx >> 7;
    const int i  = bi % NT;
    const int b  = bi / NT;
    const int t  = i + TPz;
    const float ob = outb[0];
    const float o  = outbuf[t*Mz + (b<<7) + s] + ob;
    const float In = (s == 0)
        ? input[((size_t)(b*Tz + t + 1)*Sz)*3 + 1]
        : outbuf[t*Mz + (b<<7) + s - 1] + ob;
    const float num = input[((size_t)(b*Tz + t)*Sz + s)*3 + 2] + In - o;
    const size_t base = ((size_t)(b*NT + i)*Sz + s)*3;
    out[base+0] = o;
    out[base+1] = In;
    out[base+2] = num;
}

// ---------------------------------------------------------------------------
extern "C" void kernel_launch(void* const* d_in, const int* in_sizes, int n_in,
                              void* d_out, int out_size, void* d_ws, size_t ws_size,
                              hipStream_t stream)
{
    const float* input = (const float*)d_in[0];
    const float* encWq = (const float*)d_in[1];
    const float* encWk = (const float*)d_in[2];
    const float* encWv = (const float*)d_in[3];
    const float* encWg = (const float*)d_in[4];
    const float* encbg = (const float*)d_in[5];
    const float* decWq = (const float*)d_in[6];
    const float* decWk = (const float*)d_in[7];
    const float* decWv = (const float*)d_in[8];
    const float* decWg = (const float*)d_in[9];
    const float* decbg = (const float*)d_in[10];
    const float* embW  = (const float*)d_in[11];
    const float* embb  = (const float*)d_in[12];
    const float* outW  = (const float*)d_in[13];
    const float* outb  = (const float*)d_in[14];

    char* ws = (char*)d_ws;
    size_t off = 0;
    auto alloc = [&](size_t bytes) -> void* {
        void* p = ws + off;
        off += (bytes + 255) & ~(size_t)255;
        return p;
    };
    __bf16* Wqkv_e = (__bf16*)alloc((size_t)768*256*2);
    __bf16* Wg_e   = (__bf16*)alloc((size_t)1024*512*2);
    __bf16* Wk3    = (__bf16*)alloc((size_t)1024*256*2);
    __bf16* Wg_d   = (__bf16*)alloc((size_t)1024*768*2);
    __bf16* X0     = (__bf16*)alloc((size_t)Mz*512*2);   // [ehb | dh] dbuf A
    __bf16* X1     = (__bf16*)alloc((size_t)Mz*512*2);   // dbuf B
    __bf16* q_g    = (__bf16*)alloc((size_t)Mz*256*2);
    __bf16* kv_g   = (__bf16*)alloc((size_t)Mz*512*2);
    __bf16* codeb  = (__bf16*)alloc((size_t)Mz*256*2);
    float*  ec     = (float*) alloc((size_t)Mz*256*4);
    float*  outbuf = (float*) alloc((size_t)NSTEP*Mz*4);

    hipMemsetAsync(X0, 0, (size_t)Mz*512*2, stream);
    hipMemsetAsync(X1, 0, (size_t)Mz*512*2, stream);
    hipMemsetAsync(ec, 0, (size_t)Mz*256*4, stream);
    hipMemsetAsync(outbuf, 0, (size_t)NSTEP*Mz*4, stream);

    prep2<<<6912, 256, 0, stream>>>(encWq, encWk, encWv, encWg,
                                    decWq, decWk, decWv, decWg, embW,
                                    Wqkv_e, Wg_e, Wk3, Wg_d);

    for (int t = 0; t < NSTEP; ++t) {
        __bf16* Xp = (t & 1) ? X1 : X0;
        __bf16* Xq = (t & 1) ? X0 : X1;
        // K1: enc qkv = ehb_{t-1} @ [Wq|Wk|Wv]^T
        gemm_qkv<0><<<dim3(16,6), 256, 0, stream>>>(Xp, 512, Wqkv_e, 256,
                                                    q_g, kv_g, nullptr, nullptr);
        // F_enc: attn + gates + LSTM -> ehb_t (Xq[,0:256]), ec
        f_enc<<<32, 512, 0, stream>>>(input, t, Xp, Xq, q_g, kv_g,
                                      Wg_e, encWg, encbg, ec);
        // K3: code = sig(ehb_t@embW+b); dec qkv = dh_{t-1} @ [Wq|Wk|Wv]^T
        gemm_qkv<1><<<dim3(16,8), 256, 0, stream>>>(Xq, 512, Wk3, 256,
                                                    q_g, kv_g, codeb, embb);
        // F_dec: attn + gates + LSTM + outproj -> dh_t (Xp[,256:512]), outbuf
        f_dec<<<32, 512, 0, stream>>>(Xq, Xp, q_g, kv_g, codeb, Wg_d,
                                      decbg, outW, outbuf + t*Mz);
    }
    assemble_k<<<(Bz*(NSTEP-TPz)*Sz + 255)/256, 256, 0, stream>>>(
        outbuf, input, outb, (float*)d_out);
}

// Round 5
// 2648.156 us; speedup vs baseline: 4.3992x; 1.9815x over previous
//
#include <hip/hip_runtime.h>
#include <hip/hip_bf16.h>

// Problem constants
#define Bz 16
#define Tz 32
#define Sz 128
#define TPz 4
#define Mz (Bz*Sz)          // 2048 rows
#define NSTEP (Tz-1)        // 31

typedef __bf16 bf16x8 __attribute__((ext_vector_type(8)));
typedef __bf16 bf16x4 __attribute__((ext_vector_type(4)));
typedef float  f32x4  __attribute__((ext_vector_type(4)));

__device__ __forceinline__ float sigf(float x) { return 1.f/(1.f + __expf(-x)); }

// ---------------------------------------------------------------------------
// Weight prep (fp32 in -> bf16, K-major / packed):
//  Wqkv_e [768][256] : enc [Wq|Wk|Wv]^T
//  Wg_e  [1024][512] : enc gates, K=[h(256)|ctx(256)], N gate-interleaved:
//                      n = half*512 + w*64 + g*16 + lr  ->  ch = half*128+w*16+lr, gate g
//  Wk3   [1024][256] : [embW | dec Wq | dec Wk | dec Wv]^T (all K=256)
//  Wg_d  [1024][768] : dec gates, K=[code|dh|ctx], same N packing
// ---------------------------------------------------------------------------
__global__ __launch_bounds__(256) void prep2(
    const float* __restrict__ encWq, const float* __restrict__ encWk,
    const float* __restrict__ encWv, const float* __restrict__ encWg,
    const float* __restrict__ decWq, const float* __restrict__ decWk,
    const float* __restrict__ decWv, const float* __restrict__ decWg,
    const float* __restrict__ embW,
    __bf16* __restrict__ Wqkv_e, __bf16* __restrict__ Wg_e,
    __bf16* __restrict__ Wk3,    __bf16* __restrict__ Wg_d)
{
    int id = blockIdx.x * 256 + threadIdx.x;
    if (id < 768*256) {
        int n = id >> 8, k = id & 255;
        float v = (n < 256) ? encWq[k*256 + n]
                : (n < 512) ? encWk[k*256 + (n-256)]
                            : encWv[k*256 + (n-512)];
        Wqkv_e[id] = (__bf16)v; return;
    }
    id -= 768*256;
    if (id < 1024*512) {
        int n = id >> 9, k = id & 511;
        int half = n >> 9, idx = n & 511;
        int Nt = idx >> 4, g = Nt & 3, cht = Nt >> 2, lr = idx & 15;
        int ch = half*128 + cht*16 + lr;
        int sc = g*256 + ch;
        float v = (k < 256) ? encWg[(3+k)*1024 + sc]
                            : encWg[(259+(k-256))*1024 + sc];
        Wg_e[(size_t)n*512 + k] = (__bf16)v; return;
    }
    id -= 1024*512;
    if (id < 1024*256) {
        int n = id >> 8, k = id & 255;
        float v = (n < 256) ? embW[k*256 + n]
                : (n < 512) ? decWq[k*256 + (n-256)]
                : (n < 768) ? decWk[k*256 + (n-512)]
                            : decWv[k*256 + (n-768)];
        Wk3[id] = (__bf16)v; return;
    }
    id -= 1024*256;
    if (id < 1024*768) {
        int n = id / 768, k = id % 768;
        int half = n >> 9, idx = n & 511;
        int Nt = idx >> 4, g = Nt & 3, cht = Nt >> 2, lr = idx & 15;
        int ch = half*128 + cht*16 + lr;
        int sc = g*256 + ch;
        Wg_d[(size_t)n*768 + k] = (__bf16)decWg[k*1024 + sc]; return;
    }
}

// ---------------------------------------------------------------------------
// GEMM 128x128 tile, K=256, BK=32 (verified core), A bf16 with lda.
// EPI 0 (enc qkv, N=768):  col<256 -> q_g ; col>=256 -> kv_g[col-256]
// EPI 1 (emb + dec qkv, N=1024): y<2: A+0 (ehb_t) -> sigmoid -> codeb
//        y in {2,3}: A+256 (dh) -> q_g[col-256]; y>=4: A+256 -> kv_g[col-512]
// ---------------------------------------------------------------------------
template<int EPI>
__global__ __launch_bounds__(256, 2) void gemm_qkv(
    const __bf16* __restrict__ Abase, int lda,
    const __bf16* __restrict__ BT, int K,
    __bf16* __restrict__ q_g, __bf16* __restrict__ kv_g,
    __bf16* __restrict__ codeb, const float* __restrict__ embb)
{
    __shared__ __attribute__((aligned(16))) __bf16 As[128*32];
    __shared__ __attribute__((aligned(16))) __bf16 Bs[128*32];
    const int tid  = threadIdx.x;
    const int m0   = blockIdx.x << 7;
    const int n0   = blockIdx.y << 7;
    const int lane = tid & 63;
    const int w    = tid >> 6;
    const int quad = lane >> 4, lr = lane & 15;
    const int wm   = (w >> 1) << 6, wn = (w & 1) << 6;

    const __bf16* A = Abase + ((EPI == 1 && blockIdx.y >= 2) ? 256 : 0);

    f32x4 acc[4][4];
    #pragma unroll
    for (int i = 0; i < 4; ++i)
        #pragma unroll
        for (int j = 0; j < 4; ++j) acc[i][j] = f32x4{0.f,0.f,0.f,0.f};

    const int r0 = tid >> 2;
    const int c0 = (tid & 3) << 3;
    const __bf16* gA0 = A  + (size_t)(m0 + r0)      * lda + c0;
    const __bf16* gA1 = A  + (size_t)(m0 + r0 + 64) * lda + c0;
    const __bf16* gB0 = BT + (size_t)(n0 + r0)      * K   + c0;
    const __bf16* gB1 = BT + (size_t)(n0 + r0 + 64) * K   + c0;

    for (int k0 = 0; k0 < K; k0 += 32) {
        uint4 a0 = *(const uint4*)(gA0 + k0);
        uint4 a1 = *(const uint4*)(gA1 + k0);
        uint4 b0 = *(const uint4*)(gB0 + k0);
        uint4 b1 = *(const uint4*)(gB1 + k0);
        __syncthreads();
        ((uint4*)As)[tid]       = a0;
        ((uint4*)As)[tid + 256] = a1;
        ((uint4*)Bs)[tid]       = b0;
        ((uint4*)Bs)[tid + 256] = b1;
        __syncthreads();
        bf16x8 af[4], bfr[4];
        #pragma unroll
        for (int i = 0; i < 4; ++i)
            af[i]  = *(const bf16x8*)&As[(wm + i*16 + lr)*32 + quad*8];
        #pragma unroll
        for (int i = 0; i < 4; ++i)
            bfr[i] = *(const bf16x8*)&Bs[(wn + i*16 + lr)*32 + quad*8];
        #pragma unroll
        for (int mi = 0; mi < 4; ++mi)
            #pragma unroll
            for (int ni = 0; ni < 4; ++ni)
                acc[mi][ni] = __builtin_amdgcn_mfma_f32_16x16x32_bf16(
                    af[mi], bfr[ni], acc[mi][ni], 0, 0, 0);
    }

    #pragma unroll
    for (int mi = 0; mi < 4; ++mi) {
        #pragma unroll
        for (int ni = 0; ni < 4; ++ni) {
            const int col = n0 + wn + ni*16 + lr;
            #pragma unroll
            for (int r = 0; r < 4; ++r) {
                const int row = m0 + wm + mi*16 + quad*4 + r;
                float v = acc[mi][ni][r];
                if (EPI == 0) {
                    if (col < 256) q_g[(size_t)row*256 + col] = (__bf16)v;
                    else           kv_g[(size_t)row*512 + (col-256)] = (__bf16)v;
                } else {
                    if (col < 256)
                        codeb[(size_t)row*256 + col] = (__bf16)sigf(v + embb[col]);
                    else if (col < 512)
                        q_g[(size_t)row*256 + (col-256)] = (__bf16)v;
                    else
                        kv_g[(size_t)row*512 + (col-512)] = (__bf16)v;
                }
            }
        }
    }
}

// ---------------------------------------------------------------------------
// Attention for 32 rows (one rowgroup of one batch), 512 threads.
// wave w, quad -> local row r = 4w+quad; lane lr -> 16 channels lr*16..
// head = lr>>1, head-dot via shfl_xor(1). ctx -> ctxL (stride 264, bf16).
// (math identical to verified round-3 attn_phase)
// ---------------------------------------------------------------------------
__device__ __forceinline__ void attn_dev32(
    const __bf16* __restrict__ q_g, const __bf16* __restrict__ kv_g,
    int gbatch, int s0r, int tid, __bf16* __restrict__ ctxL)
{
    const int w = tid >> 6, lane = tid & 63, quad = lane >> 4, lr = lane & 15;
    const int r = 4*w + quad;            // 0..31 local row
    const int s = s0r + r;               // 0..127 in batch
    const int ch0 = lr*16;

    float q[16];
    {
        const bf16x8* qp = (const bf16x8*)(q_g + (size_t)(gbatch + s)*256 + ch0);
        bf16x8 q0 = qp[0], q1 = qp[1];
        #pragma unroll
        for (int i = 0; i < 8; ++i) { q[i] = (float)q0[i]; q[8+i] = (float)q1[i]; }
    }
    bf16x8 zv;
    #pragma unroll
    for (int i = 0; i < 8; ++i) zv[i] = (__bf16)0.f;

    const int offs[4] = {2, 1, -1, -2};
    float sc[4];
    bf16x8 v0[4], v1[4];
    #pragma unroll
    for (int n = 0; n < 4; ++n) {
        int s2 = s + offs[n];
        bool ok = ((unsigned)s2 < 128u);
        float p = 0.f;
        if (ok) {
            const bf16x8* kp = (const bf16x8*)(kv_g + (size_t)(gbatch + s2)*512 + ch0);
            bf16x8 k0 = kp[0], k1 = kp[1];
            const bf16x8* vp = (const bf16x8*)(kv_g + (size_t)(gbatch + s2)*512 + 256 + ch0);
            v0[n] = vp[0]; v1[n] = vp[1];
            #pragma unroll
            for (int i = 0; i < 8; ++i) p += q[i]*(float)k0[i] + q[8+i]*(float)k1[i];
        } else { v0[n] = zv; v1[n] = zv; }
        p += __shfl_xor(p, 1);                 // head pair -> 32-ch dot
        sc[n] = ok ? p * 0.17677669529663687f : 0.f;
    }
    float mx = fmaxf(fmaxf(sc[0], sc[1]), fmaxf(sc[2], sc[3]));
    float se = 0.f, aw[4];
    #pragma unroll
    for (int n = 0; n < 4; ++n) { aw[n] = __expf(sc[n] - mx); se += aw[n]; }
    float inv = 1.f/se;
    float cx[16];
    #pragma unroll
    for (int i = 0; i < 16; ++i) cx[i] = 0.f;
    #pragma unroll
    for (int n = 0; n < 4; ++n)
        #pragma unroll
        for (int i = 0; i < 8; ++i) {
            cx[i]   += aw[n]*(float)v0[n][i];
            cx[8+i] += aw[n]*(float)v1[n][i];
        }
    bf16x8 o0, o1;
    #pragma unroll
    for (int i = 0; i < 8; ++i) { o0[i] = (__bf16)(cx[i]*inv); o1[i] = (__bf16)(cx[8+i]*inv); }
    *(bf16x8*)(ctxL + r*264 + ch0)     = o0;
    *(bf16x8*)(ctxL + r*264 + ch0 + 8) = o1;
}

// ---------------------------------------------------------------------------
// F_enc: block = (batch, rowgroup32, ch-half) -> 128 blocks, 512 threads.
// attn -> ctxL; gates GEMM (K=512: ehb|ctx) for 32 rows x 128 ch x 4 gates;
// LSTM (x-part folded) -> ec (fp32 global), ehb_t -> Xq[,0:256].
// ---------------------------------------------------------------------------
__global__ __launch_bounds__(512, 2) void f_enc(
    const float* __restrict__ input, int t,
    const __bf16* __restrict__ Xp, __bf16* __restrict__ Xq,
    const __bf16* __restrict__ q_g, const __bf16* __restrict__ kv_g,
    const __bf16* __restrict__ Wg,
    const float* __restrict__ encWg, const float* __restrict__ encbg,
    float* __restrict__ ec)
{
    __shared__ __attribute__((aligned(16))) __bf16 ehbL[32*264];
    __shared__ __attribute__((aligned(16))) __bf16 ctxL[32*264];
    __shared__ float xL[96];

    const int tid  = threadIdx.x;
    const int w    = tid >> 6;
    const int lane = tid & 63;
    const int quad = lane >> 4, lr = lane & 15;
    const int b    = blockIdx.x >> 3;
    const int rg   = (blockIdx.x >> 1) & 3;
    const int half = blockIdx.x & 1;
    const int gbatch = b * 128;
    const int s0r    = rg * 32;
    const int grow0  = gbatch + s0r;

    // stage ehb_{t-1} (Xp[,0:256], lda 512) rows grow0..+32 -> LDS
    #pragma unroll
    for (int it = 0; it < 2; ++it) {
        const int v = tid*2 + it, row = v >> 5, seg = v & 31;
        *(bf16x8*)&ehbL[row*264 + seg*8] =
            *(const bf16x8*)&Xp[(size_t)(grow0 + row)*512 + seg*8];
    }
    if (tid < 96) xL[tid] = input[((size_t)(b*Tz + t)*Sz + s0r)*3 + tid];

    attn_dev32(q_g, kv_g, gbatch, s0r, tid, ctxL);
    __syncthreads();

    // per-lane LSTM constants (ch owned by this lane)
    const int ch = half*128 + w*16 + lr;
    float wx0[4], wx1[4], wx2[4], bgv[4];
    #pragma unroll
    for (int g = 0; g < 4; ++g) {
        const int c = g*256 + ch;
        wx0[g] = encWg[c]; wx1[g] = encWg[1024 + c]; wx2[g] = encWg[2048 + c];
        bgv[g] = encbg[c];
    }

    // gates GEMM: 2 Mtiles x 4 gate-cols per wave, K=512
    f32x4 acc[2][4];
    #pragma unroll
    for (int m = 0; m < 2; ++m)
        #pragma unroll
        for (int g = 0; g < 4; ++g) acc[m][g] = f32x4{0.f,0.f,0.f,0.f};

    const size_t brow = (size_t)(half*512 + w*64 + lr)*512;
    for (int kk = 0; kk < 16; ++kk) {
        bf16x8 bfr[4];
        #pragma unroll
        for (int g = 0; g < 4; ++g)
            bfr[g] = *(const bf16x8*)&Wg[brow + (size_t)g*16*512 + kk*32 + quad*8];
        const __bf16* Asrc = (kk < 8) ? (ehbL + kk*32) : (ctxL + (kk-8)*32);
        bf16x8 af[2];
        #pragma unroll
        for (int m = 0; m < 2; ++m)
            af[m] = *(const bf16x8*)&Asrc[(m*16 + lr)*264 + quad*8];
        #pragma unroll
        for (int m = 0; m < 2; ++m)
            #pragma unroll
            for (int g = 0; g < 4; ++g)
                acc[m][g] = __builtin_amdgcn_mfma_f32_16x16x32_bf16(
                    af[m], bfr[g], acc[m][g], 0, 0, 0);
    }

    // LSTM epilogue
    #pragma unroll
    for (int m = 0; m < 2; ++m) {
        #pragma unroll
        for (int r = 0; r < 4; ++r) {
            const int row = m*16 + quad*4 + r;
            const float x0 = xL[row*3], x1 = xL[row*3+1], x2 = xL[row*3+2];
            const float zi = acc[m][0][r] + x0*wx0[0] + x1*wx1[0] + x2*wx2[0] + bgv[0];
            const float zf = acc[m][1][r] + x0*wx0[1] + x1*wx1[1] + x2*wx2[1] + bgv[1];
            const float zg = acc[m][2][r] + x0*wx0[2] + x1*wx1[2] + x2*wx2[2] + bgv[2];
            const float zo = acc[m][3][r] + x0*wx0[3] + x1*wx1[3] + x2*wx2[3] + bgv[3];
            const size_t ei = (size_t)(grow0 + row)*256 + ch;
            const float cn = sigf(zf)*ec[ei] + sigf(zi)*tanhf(zg);
            ec[ei] = cn;
            Xq[(size_t)(grow0 + row)*512 + ch] = (__bf16)(sigf(zo)*tanhf(cn));
        }
    }
}

// ---------------------------------------------------------------------------
// F_dec: block = (batch, rowgroup32, ch-half) -> 128 blocks.
// attn -> ctxL; gates GEMM (K=768: code|dh|ctx); LSTM (c = dh_{t-1});
// dh_t -> Xp[,256:512]; out-projection partial -> atomicAdd outbuf.
// ---------------------------------------------------------------------------
__global__ __launch_bounds__(512, 2) void f_dec(
    const __bf16* __restrict__ Xq, __bf16* __restrict__ Xp,
    const __bf16* __restrict__ q_g, const __bf16* __restrict__ kv_g,
    const __bf16* __restrict__ codeb, const __bf16* __restrict__ Wg,
    const float* __restrict__ decbg, const float* __restrict__ outW,
    float* __restrict__ outbuf)
{
    __shared__ __attribute__((aligned(16))) __bf16 codeL[32*264];
    __shared__ __attribute__((aligned(16))) __bf16 dhL[32*264];
    __shared__ __attribute__((aligned(16))) __bf16 ctxL[32*264];
    __shared__ float outredL[32*8];

    const int tid  = threadIdx.x;
    const int w    = tid >> 6;
    const int lane = tid & 63;
    const int quad = lane >> 4, lr = lane & 15;
    const int b    = blockIdx.x >> 3;
    const int rg   = (blockIdx.x >> 1) & 3;
    const int half = blockIdx.x & 1;
    const int gbatch = b * 128;
    const int s0r    = rg * 32;
    const int grow0  = gbatch + s0r;

    // stage code (codeb, lda 256) and dh_{t-1} (Xq[,256:512]) -> LDS
    #pragma unroll
    for (int it = 0; it < 2; ++it) {
        const int v = tid*2 + it, row = v >> 5, seg = v & 31;
        *(bf16x8*)&codeL[row*264 + seg*8] =
            *(const bf16x8*)&codeb[(size_t)(grow0 + row)*256 + seg*8];
        *(bf16x8*)&dhL[row*264 + seg*8] =
            *(const bf16x8*)&Xq[(size_t)(grow0 + row)*512 + 256 + seg*8];
    }

    attn_dev32(q_g, kv_g, gbatch, s0r, tid, ctxL);
    __syncthreads();

    const int ch = half*128 + w*16 + lr;
    float bgv[4];
    #pragma unroll
    for (int g = 0; g < 4; ++g) bgv[g] = decbg[g*256 + ch];
    const float ow = outW[ch];

    f32x4 acc[2][4];
    #pragma unroll
    for (int m = 0; m < 2; ++m)
        #pragma unroll
        for (int g = 0; g < 4; ++g) acc[m][g] = f32x4{0.f,0.f,0.f,0.f};

    const size_t brow = (size_t)(half*512 + w*64 + lr)*768;
    for (int kk = 0; kk < 24; ++kk) {
        bf16x8 bfr[4];
        #pragma unroll
        for (int g = 0; g < 4; ++g)
            bfr[g] = *(const bf16x8*)&Wg[brow + (size_t)g*16*768 + kk*32 + quad*8];
        const __bf16* Asrc = (kk < 8) ? (codeL + kk*32)
                           : (kk < 16) ? (dhL + (kk-8)*32)
                                       : (ctxL + (kk-16)*32);
        bf16x8 af[2];
        #pragma unroll
        for (int m = 0; m < 2; ++m)
            af[m] = *(const bf16x8*)&Asrc[(m*16 + lr)*264 + quad*8];
        #pragma unroll
        for (int m = 0; m < 2; ++m)
            #pragma unroll
            for (int g = 0; g < 4; ++g)
                acc[m][g] = __builtin_amdgcn_mfma_f32_16x16x32_bf16(
                    af[m], bfr[g], acc[m][g], 0, 0, 0);
    }

    // LSTM + out projection
    #pragma unroll
    for (int m = 0; m < 2; ++m) {
        #pragma unroll
        for (int r = 0; r < 4; ++r) {
            const int row = m*16 + quad*4 + r;
            const float zi = acc[m][0][r] + bgv[0];
            const float zf = acc[m][1][r] + bgv[1];
            const float zg = acc[m][2][r] + bgv[2];
            const float zo = acc[m][3][r] + bgv[3];
            const float c_old = (float)dhL[row*264 + ch];
            const float cn = sigf(zf)*c_old + sigf(zi)*tanhf(zg);
            const float h  = sigf(zo)*tanhf(cn);
            Xp[(size_t)(grow0 + row)*512 + 256 + ch] = (__bf16)h;
            float pv = h * ow;
            pv += __shfl_xor(pv, 1); pv += __shfl_xor(pv, 2);
            pv += __shfl_xor(pv, 4); pv += __shfl_xor(pv, 8);
            if (lr == 0) outredL[row*8 + w] = pv;
        }
    }
    __syncthreads();
    if (tid < 32) {
        float s = 0.f;
        #pragma unroll
        for (int ww = 0; ww < 8; ++ww) s += outredL[tid*8 + ww];
        atomicAdd(&outbuf[grow0 + tid], s);
    }
}

// ---------------------------------------------------------------------------
// Final assembly: out / In / num for scan steps t in [TP, T-2], fp32 output.
// ---------------------------------------------------------------------------
__global__ __launch_bounds__(256) void assemble_k(
    const float* __restrict__ outbuf, const float* __restrict__ input,
    const float* __restrict__ outb, float* __restrict__ out)
{
    const int idx = blockIdx.x*256 + threadIdx.x;
    const int NT = NSTEP - TPz;                 // 27
    if (idx >= Bz*NT*Sz) return;
    const int s  = idx & 127;
    const int bi = idx >> 7;
    const int i  = bi % NT;
    const int b  = bi / NT;
    const int t  = i + TPz;
    const float ob = outb[0];
    const float o  = outbuf[t*Mz + (b<<7) + s] + ob;
    const float In = (s == 0)
        ? input[((size_t)(b*Tz + t + 1)*Sz)*3 + 1]
        : outbuf[t*Mz + (b<<7) + s - 1] + ob;
    const float num = input[((size_t)(b*Tz + t)*Sz + s)*3 + 2] + In - o;
    const size_t base = ((size_t)(b*NT + i)*Sz + s)*3;
    out[base+0] = o;
    out[base+1] = In;
    out[base+2] = num;
}

// ---------------------------------------------------------------------------
extern "C" void kernel_launch(void* const* d_in, const int* in_sizes, int n_in,
                              void* d_out, int out_size, void* d_ws, size_t ws_size,
                              hipStream_t stream)
{
    const float* input = (const float*)d_in[0];
    const float* encWq = (const float*)d_in[1];
    const float* encWk = (const float*)d_in[2];
    const float* encWv = (const float*)d_in[3];
    const float* encWg = (const float*)d_in[4];
    const float* encbg = (const float*)d_in[5];
    const float* decWq = (const float*)d_in[6];
    const float* decWk = (const float*)d_in[7];
    const float* decWv = (const float*)d_in[8];
    const float* decWg = (const float*)d_in[9];
    const float* decbg = (const float*)d_in[10];
    const float* embW  = (const float*)d_in[11];
    const float* embb  = (const float*)d_in[12];
    const float* outW  = (const float*)d_in[13];
    const float* outb  = (const float*)d_in[14];

    char* ws = (char*)d_ws;
    size_t off = 0;
    auto alloc = [&](size_t bytes) -> void* {
        void* p = ws + off;
        off += (bytes + 255) & ~(size_t)255;
        return p;
    };
    __bf16* Wqkv_e = (__bf16*)alloc((size_t)768*256*2);
    __bf16* Wg_e   = (__bf16*)alloc((size_t)1024*512*2);
    __bf16* Wk3    = (__bf16*)alloc((size_t)1024*256*2);
    __bf16* Wg_d   = (__bf16*)alloc((size_t)1024*768*2);
    __bf16* X0     = (__bf16*)alloc((size_t)Mz*512*2);   // [ehb | dh] dbuf A
    __bf16* X1     = (__bf16*)alloc((size_t)Mz*512*2);   // dbuf B
    __bf16* q_g    = (__bf16*)alloc((size_t)Mz*256*2);
    __bf16* kv_g   = (__bf16*)alloc((size_t)Mz*512*2);
    __bf16* codeb  = (__bf16*)alloc((size_t)Mz*256*2);
    float*  ec     = (float*) alloc((size_t)Mz*256*4);
    float*  outbuf = (float*) alloc((size_t)NSTEP*Mz*4);

    hipMemsetAsync(X0, 0, (size_t)Mz*512*2, stream);
    hipMemsetAsync(X1, 0, (size_t)Mz*512*2, stream);
    hipMemsetAsync(ec, 0, (size_t)Mz*256*4, stream);
    hipMemsetAsync(outbuf, 0, (size_t)NSTEP*Mz*4, stream);

    prep2<<<6912, 256, 0, stream>>>(encWq, encWk, encWv, encWg,
                                    decWq, decWk, decWv, decWg, embW,
                                    Wqkv_e, Wg_e, Wk3, Wg_d);

    for (int t = 0; t < NSTEP; ++t) {
        __bf16* Xp = (t & 1) ? X1 : X0;
        __bf16* Xq = (t & 1) ? X0 : X1;
        // K1: enc qkv = ehb_{t-1} @ [Wq|Wk|Wv]^T
        gemm_qkv<0><<<dim3(16,6), 256, 0, stream>>>(Xp, 512, Wqkv_e, 256,
                                                    q_g, kv_g, nullptr, nullptr);
        // F_enc: attn + gates + LSTM -> ehb_t (Xq[,0:256]), ec
        f_enc<<<128, 512, 0, stream>>>(input, t, Xp, Xq, q_g, kv_g,
                                       Wg_e, encWg, encbg, ec);
        // K3: code = sig(ehb_t@embW+b); dec qkv = dh_{t-1} @ [Wq|Wk|Wv]^T
        gemm_qkv<1><<<dim3(16,8), 256, 0, stream>>>(Xq, 512, Wk3, 256,
                                                    q_g, kv_g, codeb, embb);
        // F_dec: attn + gates + LSTM + outproj -> dh_t (Xp[,256:512]), outbuf
        f_dec<<<128, 512, 0, stream>>>(Xq, Xp, q_g, kv_g, codeb, Wg_d,
                                       decbg, outW, outbuf + t*Mz);
    }
    assemble_k<<<(Bz*(NSTEP-TPz)*Sz + 255)/256, 256, 0, stream>>>(
        outbuf, input, outb, (float*)d_out);
}

// Round 6
// 1621.519 us; speedup vs baseline: 7.1845x; 1.6331x over previous
//
#include <hip/hip_runtime.h>
#include <hip/hip_bf16.h>

// Problem constants
#define Bz 16
#define Tz 32
#define Sz 128
#define TPz 4
#define Mz (Bz*Sz)          // 2048 rows
#define NSTEP (Tz-1)        // 31

typedef __bf16 bf16x8 __attribute__((ext_vector_type(8)));
typedef float  f32x4  __attribute__((ext_vector_type(4)));

__device__ __forceinline__ float sigf(float x) { return 1.f/(1.f + __expf(-x)); }

// ---------------------------------------------------------------------------
// Weight prep (fp32 -> bf16, K-major / packed):
//  Wqkv_e [768][256] : enc [Wq|Wk|Wv]^T
//  Wqkv_d [768][256] : dec [Wq|Wk|Wv]^T
//  Wg_e  [1024][512] : enc gates, K=[h|ctx]; n = cht*64 + g*16 + lr,
//                      ch = cht*16+lr (cht 0..15), src col = g*256+ch
//  WTemb [256][256]  : emb_W^T
//  Wg_d  [1024][768] : dec gates, K=[code|dh|ctx], same n packing
// ---------------------------------------------------------------------------
__global__ __launch_bounds__(256) void prep2(
    const float* __restrict__ encWq, const float* __restrict__ encWk,
    const float* __restrict__ encWv, const float* __restrict__ encWg,
    const float* __restrict__ decWq, const float* __restrict__ decWk,
    const float* __restrict__ decWv, const float* __restrict__ decWg,
    const float* __restrict__ embW,
    __bf16* __restrict__ Wqkv_e, __bf16* __restrict__ Wqkv_d,
    __bf16* __restrict__ Wg_e,   __bf16* __restrict__ WTemb,
    __bf16* __restrict__ Wg_d)
{
    int id = blockIdx.x * 256 + threadIdx.x;
    if (id < 768*256) {
        int n = id >> 8, k = id & 255;
        float v = (n < 256) ? encWq[k*256 + n]
                : (n < 512) ? encWk[k*256 + (n-256)]
                            : encWv[k*256 + (n-512)];
        Wqkv_e[id] = (__bf16)v; return;
    }
    id -= 768*256;
    if (id < 768*256) {
        int n = id >> 8, k = id & 255;
        float v = (n < 256) ? decWq[k*256 + n]
                : (n < 512) ? decWk[k*256 + (n-256)]
                            : decWv[k*256 + (n-512)];
        Wqkv_d[id] = (__bf16)v; return;
    }
    id -= 768*256;
    if (id < 1024*512) {
        int n = id >> 9, k = id & 511;
        int cht = n >> 6, g = (n >> 4) & 3, lr = n & 15;
        int ch = cht*16 + lr, sc = g*256 + ch;
        float v = (k < 256) ? encWg[(3+k)*1024 + sc]
                            : encWg[(259+(k-256))*1024 + sc];
        Wg_e[(size_t)n*512 + k] = (__bf16)v; return;
    }
    id -= 1024*512;
    if (id < 256*256) {
        int n = id >> 8, k = id & 255;
        WTemb[id] = (__bf16)embW[k*256 + n]; return;
    }
    id -= 256*256;
    if (id < 1024*768) {
        int n = id / 768, k = id % 768;
        int cht = n >> 6, g = (n >> 4) & 3, lr = n & 15;
        int ch = cht*16 + lr, sc = g*256 + ch;
        Wg_d[(size_t)n*768 + k] = (__bf16)decWg[k*1024 + sc]; return;
    }
}

// ---------------------------------------------------------------------------
// D1: combo qkv GEMM (verified 128x128 core, K=256, lda=512).
// y<6: enc (A=Xp[,0:256], B=Wqkv_e) -> q_e / kv_e
// y>=6: dec (A=Xp[,256:512], B=Wqkv_d) -> q_d / kv_d
// ---------------------------------------------------------------------------
__global__ __launch_bounds__(256, 2) void gemm_qkv2(
    const __bf16* __restrict__ Xp,
    const __bf16* __restrict__ We, const __bf16* __restrict__ Wd,
    __bf16* __restrict__ q_e, __bf16* __restrict__ kv_e,
    __bf16* __restrict__ q_d, __bf16* __restrict__ kv_d)
{
    __shared__ __attribute__((aligned(16))) __bf16 As[128*32];
    __shared__ __attribute__((aligned(16))) __bf16 Bs[128*32];
    const int tid  = threadIdx.x;
    const bool dec = blockIdx.y >= 6;
    const int m0   = blockIdx.x << 7;
    const int n0   = (dec ? (blockIdx.y - 6) : blockIdx.y) << 7;
    const int lane = tid & 63;
    const int w    = tid >> 6;
    const int quad = lane >> 4, lr = lane & 15;
    const int wm   = (w >> 1) << 6, wn = (w & 1) << 6;

    const __bf16* A  = Xp + (dec ? 256 : 0);
    const __bf16* BT = dec ? Wd : We;
    __bf16* qo  = dec ? q_d  : q_e;
    __bf16* kvo = dec ? kv_d : kv_e;

    f32x4 acc[4][4];
    #pragma unroll
    for (int i = 0; i < 4; ++i)
        #pragma unroll
        for (int j = 0; j < 4; ++j) acc[i][j] = f32x4{0.f,0.f,0.f,0.f};

    const int r0 = tid >> 2;
    const int c0 = (tid & 3) << 3;
    const __bf16* gA0 = A  + (size_t)(m0 + r0)      * 512 + c0;
    const __bf16* gA1 = A  + (size_t)(m0 + r0 + 64) * 512 + c0;
    const __bf16* gB0 = BT + (size_t)(n0 + r0)      * 256 + c0;
    const __bf16* gB1 = BT + (size_t)(n0 + r0 + 64) * 256 + c0;

    for (int k0 = 0; k0 < 256; k0 += 32) {
        uint4 a0 = *(const uint4*)(gA0 + k0);
        uint4 a1 = *(const uint4*)(gA1 + k0);
        uint4 b0 = *(const uint4*)(gB0 + k0);
        uint4 b1 = *(const uint4*)(gB1 + k0);
        __syncthreads();
        ((uint4*)As)[tid]       = a0;
        ((uint4*)As)[tid + 256] = a1;
        ((uint4*)Bs)[tid]       = b0;
        ((uint4*)Bs)[tid + 256] = b1;
        __syncthreads();
        bf16x8 af[4], bfr[4];
        #pragma unroll
        for (int i = 0; i < 4; ++i)
            af[i]  = *(const bf16x8*)&As[(wm + i*16 + lr)*32 + quad*8];
        #pragma unroll
        for (int i = 0; i < 4; ++i)
            bfr[i] = *(const bf16x8*)&Bs[(wn + i*16 + lr)*32 + quad*8];
        #pragma unroll
        for (int mi = 0; mi < 4; ++mi)
            #pragma unroll
            for (int ni = 0; ni < 4; ++ni)
                acc[mi][ni] = __builtin_amdgcn_mfma_f32_16x16x32_bf16(
                    af[mi], bfr[ni], acc[mi][ni], 0, 0, 0);
    }

    #pragma unroll
    for (int mi = 0; mi < 4; ++mi) {
        #pragma unroll
        for (int ni = 0; ni < 4; ++ni) {
            const int col = n0 + wn + ni*16 + lr;
            #pragma unroll
            for (int r = 0; r < 4; ++r) {
                const int row = m0 + wm + mi*16 + quad*4 + r;
                float v = acc[mi][ni][r];
                if (col < 256) qo[(size_t)row*256 + col] = (__bf16)v;
                else           kvo[(size_t)row*512 + (col-256)] = (__bf16)v;
            }
        }
    }
}

// ---------------------------------------------------------------------------
// Attention for 32 rows (verified round-5 core). ctx -> ctxL stride 264.
// ---------------------------------------------------------------------------
__device__ __forceinline__ void attn_dev32(
    const __bf16* __restrict__ q_g, const __bf16* __restrict__ kv_g,
    int gbatch, int s0r, int tid, __bf16* __restrict__ ctxL)
{
    const int w = tid >> 6, lane = tid & 63, quad = lane >> 4, lr = lane & 15;
    const int r = 4*w + quad;
    const int s = s0r + r;
    const int ch0 = lr*16;

    float q[16];
    {
        const bf16x8* qp = (const bf16x8*)(q_g + (size_t)(gbatch + s)*256 + ch0);
        bf16x8 q0 = qp[0], q1 = qp[1];
        #pragma unroll
        for (int i = 0; i < 8; ++i) { q[i] = (float)q0[i]; q[8+i] = (float)q1[i]; }
    }
    bf16x8 zv;
    #pragma unroll
    for (int i = 0; i < 8; ++i) zv[i] = (__bf16)0.f;

    const int offs[4] = {2, 1, -1, -2};
    float sc[4];
    bf16x8 v0[4], v1[4];
    #pragma unroll
    for (int n = 0; n < 4; ++n) {
        int s2 = s + offs[n];
        bool ok = ((unsigned)s2 < 128u);
        float p = 0.f;
        if (ok) {
            const bf16x8* kp = (const bf16x8*)(kv_g + (size_t)(gbatch + s2)*512 + ch0);
            bf16x8 k0 = kp[0], k1 = kp[1];
            const bf16x8* vp = (const bf16x8*)(kv_g + (size_t)(gbatch + s2)*512 + 256 + ch0);
            v0[n] = vp[0]; v1[n] = vp[1];
            #pragma unroll
            for (int i = 0; i < 8; ++i) p += q[i]*(float)k0[i] + q[8+i]*(float)k1[i];
        } else { v0[n] = zv; v1[n] = zv; }
        p += __shfl_xor(p, 1);
        sc[n] = ok ? p * 0.17677669529663687f : 0.f;
    }
    float mx = fmaxf(fmaxf(sc[0], sc[1]), fmaxf(sc[2], sc[3]));
    float se = 0.f, aw[4];
    #pragma unroll
    for (int n = 0; n < 4; ++n) { aw[n] = __expf(sc[n] - mx); se += aw[n]; }
    float inv = 1.f/se;
    float cx[16];
    #pragma unroll
    for (int i = 0; i < 16; ++i) cx[i] = 0.f;
    #pragma unroll
    for (int n = 0; n < 4; ++n)
        #pragma unroll
        for (int i = 0; i < 8; ++i) {
            cx[i]   += aw[n]*(float)v0[n][i];
            cx[8+i] += aw[n]*(float)v1[n][i];
        }
    bf16x8 o0, o1;
    #pragma unroll
    for (int i = 0; i < 8; ++i) { o0[i] = (__bf16)(cx[i]*inv); o1[i] = (__bf16)(cx[8+i]*inv); }
    *(bf16x8*)(ctxL + r*264 + ch0)     = o0;
    *(bf16x8*)(ctxL + r*264 + ch0 + 8) = o1;
}

// ---------------------------------------------------------------------------
// F_enc: 256 blocks = (b, rg 0..3, quarter 0..3), 512 threads.
// attn -> ctxL; gates GEMM K=512 (ehbL|ctxL) x 256 gate-cols (own quarter),
// B double-buffered LDS-staged coalesced; LSTM -> ec, ehb_t (Xq[,0:256]).
// ---------------------------------------------------------------------------
__global__ __launch_bounds__(512, 2) void f_enc(
    const float* __restrict__ input, int t,
    const __bf16* __restrict__ Xp, __bf16* __restrict__ Xq,
    const __bf16* __restrict__ q_e, const __bf16* __restrict__ kv_e,
    const __bf16* __restrict__ Wg,
    const float* __restrict__ encWg, const float* __restrict__ encbg,
    float* __restrict__ ec)
{
    __shared__ __attribute__((aligned(16))) __bf16 ehbL[32*264];
    __shared__ __attribute__((aligned(16))) __bf16 ctxL[32*264];
    __shared__ __attribute__((aligned(16))) __bf16 Bs[2][256*32];
    __shared__ float xL[96];

    const int tid  = threadIdx.x;
    const int w    = tid >> 6;
    const int lane = tid & 63;
    const int quad = lane >> 4, lr = lane & 15;
    const int b    = blockIdx.x >> 4;
    const int rg   = (blockIdx.x >> 2) & 3;
    const int qt   = blockIdx.x & 3;
    const int gbatch = b*128, s0r = rg*32, grow0 = gbatch + s0r;

    #pragma unroll
    for (int it = 0; it < 2; ++it) {
        const int v = tid*2 + it, row = v >> 5, seg = v & 31;
        *(bf16x8*)&ehbL[row*264 + seg*8] =
            *(const bf16x8*)&Xp[(size_t)(grow0 + row)*512 + seg*8];
    }
    if (tid < 96) xL[tid] = input[((size_t)(b*Tz + t)*Sz + s0r)*3 + tid];

    attn_dev32(q_e, kv_e, gbatch, s0r, tid, ctxL);

    // B staging: 256 n-rows x 32 k per chunk, 32 B / thread
    const int br = tid >> 1, bseg = (tid & 1) << 4;
    const __bf16* bgl = Wg + (size_t)(qt*256 + br)*512 + bseg;
    uint4 p0 = *(const uint4*)(bgl);
    uint4 p1 = *(const uint4*)(bgl + 8);
    *(uint4*)&Bs[0][br*32 + bseg]     = p0;
    *(uint4*)&Bs[0][br*32 + bseg + 8] = p1;

    const int mt = w >> 2, ct = w & 3;
    f32x4 acc[4];
    #pragma unroll
    for (int g = 0; g < 4; ++g) acc[g] = f32x4{0.f,0.f,0.f,0.f};

    for (int kk = 0; kk < 16; ++kk) {
        __syncthreads();
        if (kk < 15) {
            p0 = *(const uint4*)(bgl + (kk+1)*32);
            p1 = *(const uint4*)(bgl + (kk+1)*32 + 8);
        }
        const __bf16* Asrc = (kk < 8) ? (ehbL + kk*32) : (ctxL + (kk-8)*32);
        bf16x8 af = *(const bf16x8*)&Asrc[(mt*16 + lr)*264 + quad*8];
        const __bf16* bb = &Bs[kk & 1][0];
        #pragma unroll
        for (int g = 0; g < 4; ++g) {
            bf16x8 bf = *(const bf16x8*)&bb[((ct*4 + g)*16 + lr)*32 + quad*8];
            acc[g] = __builtin_amdgcn_mfma_f32_16x16x32_bf16(af, bf, acc[g], 0,0,0);
        }
        if (kk < 15) {
            *(uint4*)&Bs[(kk+1)&1][br*32 + bseg]     = p0;
            *(uint4*)&Bs[(kk+1)&1][br*32 + bseg + 8] = p1;
        }
    }

    // LSTM epilogue: wave owns 16 rows (mt) x 16 ch (lr, within ct of quarter)
    const int ch = qt*64 + ct*16 + lr;
    float wx0[4], wx1[4], wx2[4], bgv[4];
    #pragma unroll
    for (int g = 0; g < 4; ++g) {
        const int c = g*256 + ch;
        wx0[g] = encWg[c]; wx1[g] = encWg[1024 + c]; wx2[g] = encWg[2048 + c];
        bgv[g] = encbg[c];
    }
    #pragma unroll
    for (int r = 0; r < 4; ++r) {
        const int row = mt*16 + quad*4 + r;
        const float x0 = xL[row*3], x1 = xL[row*3+1], x2 = xL[row*3+2];
        const float zi = acc[0][r] + x0*wx0[0] + x1*wx1[0] + x2*wx2[0] + bgv[0];
        const float zf = acc[1][r] + x0*wx0[1] + x1*wx1[1] + x2*wx2[1] + bgv[1];
        const float zg = acc[2][r] + x0*wx0[2] + x1*wx1[2] + x2*wx2[2] + bgv[2];
        const float zo = acc[3][r] + x0*wx0[3] + x1*wx1[3] + x2*wx2[3] + bgv[3];
        const size_t ei = (size_t)(grow0 + row)*256 + ch;
        const float cn = sigf(zf)*ec[ei] + sigf(zi)*tanhf(zg);
        ec[ei] = cn;
        Xq[(size_t)(grow0 + row)*512 + ch] = (__bf16)(sigf(zo)*tanhf(cn));
    }
}

// ---------------------------------------------------------------------------
// F_dec: 256 blocks = (b, rg, quarter), 512 threads.
// P0: code = sig(ehb_t @ embW + b) -> codeL (M=32,N=256,K=256, B staged).
// attn -> ctxL; P1: gates K=768 (codeL|dhL|ctxL) x own quarter cols;
// LSTM (c=dh_{t-1}) -> dh_t (Xq[,256:512]); outproj partial -> atomicAdd.
// ---------------------------------------------------------------------------
__global__ __launch_bounds__(512, 2) void f_dec(
    const __bf16* __restrict__ Xp, __bf16* __restrict__ Xq,
    const __bf16* __restrict__ q_d, const __bf16* __restrict__ kv_d,
    const __bf16* __restrict__ Wemb, const __bf16* __restrict__ Wg,
    const float* __restrict__ embb, const float* __restrict__ decbg,
    const float* __restrict__ outW, float* __restrict__ outbuf)
{
    __shared__ __attribute__((aligned(16))) __bf16 ehbtL[32*264];
    __shared__ __attribute__((aligned(16))) __bf16 codeL[32*264];
    __shared__ __attribute__((aligned(16))) __bf16 dhL[32*264];
    __shared__ __attribute__((aligned(16))) __bf16 ctxL[32*264];
    __shared__ __attribute__((aligned(16))) __bf16 Bs[2][256*32];
    __shared__ float outredL[32*4];

    const int tid  = threadIdx.x;
    const int w    = tid >> 6;
    const int lane = tid & 63;
    const int quad = lane >> 4, lr = lane & 15;
    const int b    = blockIdx.x >> 4;
    const int rg   = (blockIdx.x >> 2) & 3;
    const int qt   = blockIdx.x & 3;
    const int gbatch = b*128, s0r = rg*32, grow0 = gbatch + s0r;

    #pragma unroll
    for (int it = 0; it < 2; ++it) {
        const int v = tid*2 + it, row = v >> 5, seg = v & 31;
        *(bf16x8*)&ehbtL[row*264 + seg*8] =
            *(const bf16x8*)&Xq[(size_t)(grow0 + row)*512 + seg*8];
        *(bf16x8*)&dhL[row*264 + seg*8] =
            *(const bf16x8*)&Xp[(size_t)(grow0 + row)*512 + 256 + seg*8];
    }

    attn_dev32(q_d, kv_d, gbatch, s0r, tid, ctxL);

    const int br = tid >> 1, bseg = (tid & 1) << 4;
    const __bf16* egl = Wemb + (size_t)br*256 + bseg;
    const __bf16* dgl = Wg + (size_t)(qt*256 + br)*768 + bseg;

    // P0: code GEMM (8 kk), dbuf; at kk==7 preload P1 chunk 0 into Bs[0]
    uint4 p0 = *(const uint4*)(egl);
    uint4 p1 = *(const uint4*)(egl + 8);
    *(uint4*)&Bs[0][br*32 + bseg]     = p0;
    *(uint4*)&Bs[0][br*32 + bseg + 8] = p1;

    f32x4 cacc[2][2];
    #pragma unroll
    for (int m = 0; m < 2; ++m)
        #pragma unroll
        for (int i = 0; i < 2; ++i) cacc[m][i] = f32x4{0.f,0.f,0.f,0.f};

    for (int kk = 0; kk < 8; ++kk) {
        __syncthreads();
        const __bf16* nsrc = (kk < 7) ? (egl + (kk+1)*32) : dgl;
        p0 = *(const uint4*)(nsrc);
        p1 = *(const uint4*)(nsrc + 8);
        const __bf16* bb = &Bs[kk & 1][0];
        #pragma unroll
        for (int m = 0; m < 2; ++m) {
            bf16x8 af = *(const bf16x8*)&ehbtL[(m*16 + lr)*264 + kk*32 + quad*8];
            #pragma unroll
            for (int i = 0; i < 2; ++i) {
                bf16x8 bf = *(const bf16x8*)&bb[((w*2 + i)*16 + lr)*32 + quad*8];
                cacc[m][i] = __builtin_amdgcn_mfma_f32_16x16x32_bf16(af, bf, cacc[m][i], 0,0,0);
            }
        }
        *(uint4*)&Bs[(kk+1)&1][br*32 + bseg]     = p0;
        *(uint4*)&Bs[(kk+1)&1][br*32 + bseg + 8] = p1;
    }
    // code epilogue -> codeL (sigmoid)
    #pragma unroll
    for (int m = 0; m < 2; ++m)
        #pragma unroll
        for (int i = 0; i < 2; ++i) {
            const int col = (w*2 + i)*16 + lr;
            const float bb = embb[col];
            #pragma unroll
            for (int r = 0; r < 4; ++r) {
                const int row = m*16 + quad*4 + r;
                codeL[row*264 + col] = (__bf16)sigf(cacc[m][i][r] + bb);
            }
        }

    // P1: gates GEMM K=768 (24 kk), Bs[0] already holds chunk 0
    const int mt = w >> 2, ct = w & 3;
    f32x4 acc[4];
    #pragma unroll
    for (int g = 0; g < 4; ++g) acc[g] = f32x4{0.f,0.f,0.f,0.f};

    for (int kk = 0; kk < 24; ++kk) {
        __syncthreads();
        if (kk < 23) {
            p0 = *(const uint4*)(dgl + (kk+1)*32);
            p1 = *(const uint4*)(dgl + (kk+1)*32 + 8);
        }
        const __bf16* Asrc = (kk < 8)  ? (codeL + kk*32)
                           : (kk < 16) ? (dhL + (kk-8)*32)
                                       : (ctxL + (kk-16)*32);
        bf16x8 af = *(const bf16x8*)&Asrc[(mt*16 + lr)*264 + quad*8];
        const __bf16* bb = &Bs[kk & 1][0];
        #pragma unroll
        for (int g = 0; g < 4; ++g) {
            bf16x8 bf = *(const bf16x8*)&bb[((ct*4 + g)*16 + lr)*32 + quad*8];
            acc[g] = __builtin_amdgcn_mfma_f32_16x16x32_bf16(af, bf, acc[g], 0,0,0);
        }
        if (kk < 23) {
            *(uint4*)&Bs[(kk+1)&1][br*32 + bseg]     = p0;
            *(uint4*)&Bs[(kk+1)&1][br*32 + bseg + 8] = p1;
        }
    }

    // LSTM + out projection
    const int ch = qt*64 + ct*16 + lr;
    float bgv[4];
    #pragma unroll
    for (int g = 0; g < 4; ++g) bgv[g] = decbg[g*256 + ch];
    const float ow = outW[ch];

    #pragma unroll
    for (int r = 0; r < 4; ++r) {
        const int row = mt*16 + quad*4 + r;
        const float zi = acc[0][r] + bgv[0];
        const float zf = acc[1][r] + bgv[1];
        const float zg = acc[2][r] + bgv[2];
        const float zo = acc[3][r] + bgv[3];
        const float c_old = (float)dhL[row*264 + ch];
        const float cn = sigf(zf)*c_old + sigf(zi)*tanhf(zg);
        const float h  = sigf(zo)*tanhf(cn);
        Xq[(size_t)(grow0 + row)*512 + 256 + ch] = (__bf16)h;
        float pv = h * ow;
        pv += __shfl_xor(pv, 1); pv += __shfl_xor(pv, 2);
        pv += __shfl_xor(pv, 4); pv += __shfl_xor(pv, 8);
        if (lr == 0) outredL[row*4 + ct] = pv;
    }
    __syncthreads();
    if (tid < 32) {
        float s = outredL[tid*4] + outredL[tid*4+1] + outredL[tid*4+2] + outredL[tid*4+3];
        atomicAdd(&outbuf[grow0 + tid], s);
    }
}

// ---------------------------------------------------------------------------
// Final assembly (unchanged, verified)
// ---------------------------------------------------------------------------
__global__ __launch_bounds__(256) void assemble_k(
    const float* __restrict__ outbuf, const float* __restrict__ input,
    const float* __restrict__ outb, float* __restrict__ out)
{
    const int idx = blockIdx.x*256 + threadIdx.x;
    const int NT = NSTEP - TPz;                 // 27
    if (idx >= Bz*NT*Sz) return;
    const int s  = idx & 127;
    const int bi = idx >> 7;
    const int i  = bi % NT;
    const int b  = bi / NT;
    const int t  = i + TPz;
    const float ob = outb[0];
    const float o  = outbuf[t*Mz + (b<<7) + s] + ob;
    const float In = (s == 0)
        ? input[((size_t)(b*Tz + t + 1)*Sz)*3 + 1]
        : outbuf[t*Mz + (b<<7) + s - 1] + ob;
    const float num = input[((size_t)(b*Tz + t)*Sz + s)*3 + 2] + In - o;
    const size_t base = ((size_t)(b*NT + i)*Sz + s)*3;
    out[base+0] = o;
    out[base+1] = In;
    out[base+2] = num;
}

// ---------------------------------------------------------------------------
extern "C" void kernel_launch(void* const* d_in, const int* in_sizes, int n_in,
                              void* d_out, int out_size, void* d_ws, size_t ws_size,
                              hipStream_t stream)
{
    const float* input = (const float*)d_in[0];
    const float* encWq = (const float*)d_in[1];
    const float* encWk = (const float*)d_in[2];
    const float* encWv = (const float*)d_in[3];
    const float* encWg = (const float*)d_in[4];
    const float* encbg = (const float*)d_in[5];
    const float* decWq = (const float*)d_in[6];
    const float* decWk = (const float*)d_in[7];
    const float* decWv = (const float*)d_in[8];
    const float* decWg = (const float*)d_in[9];
    const float* decbg = (const float*)d_in[10];
    const float* embW  = (const float*)d_in[11];
    const float* embb  = (const float*)d_in[12];
    const float* outW  = (const float*)d_in[13];
    const float* outb  = (const float*)d_in[14];

    char* ws = (char*)d_ws;
    size_t off = 0;
    auto alloc = [&](size_t bytes) -> void* {
        void* p = ws + off;
        off += (bytes + 255) & ~(size_t)255;
        return p;
    };
    __bf16* Wqkv_e = (__bf16*)alloc((size_t)768*256*2);
    __bf16* Wqkv_d = (__bf16*)alloc((size_t)768*256*2);
    __bf16* Wg_e   = (__bf16*)alloc((size_t)1024*512*2);
    __bf16* WTemb  = (__bf16*)alloc((size_t)256*256*2);
    __bf16* Wg_d   = (__bf16*)alloc((size_t)1024*768*2);
    __bf16* X0     = (__bf16*)alloc((size_t)Mz*512*2);   // [ehb | dh] dbuf A
    __bf16* X1     = (__bf16*)alloc((size_t)Mz*512*2);   // dbuf B
    __bf16* q_e    = (__bf16*)alloc((size_t)Mz*256*2);
    __bf16* kv_e   = (__bf16*)alloc((size_t)Mz*512*2);
    __bf16* q_d    = (__bf16*)alloc((size_t)Mz*256*2);
    __bf16* kv_d   = (__bf16*)alloc((size_t)Mz*512*2);
    float*  ec     = (float*) alloc((size_t)Mz*256*4);
    float*  outbuf = (float*) alloc((size_t)NSTEP*Mz*4);

    hipMemsetAsync(X0, 0, (size_t)Mz*512*2, stream);
    hipMemsetAsync(ec, 0, (size_t)Mz*256*4, stream);
    hipMemsetAsync(outbuf, 0, (size_t)NSTEP*Mz*4, stream);

    prep2<<<6912, 256, 0, stream>>>(encWq, encWk, encWv, encWg,
                                    decWq, decWk, decWv, decWg, embW,
                                    Wqkv_e, Wqkv_d, Wg_e, WTemb, Wg_d);

    for (int t = 0; t < NSTEP; ++t) {
        __bf16* Xp = (t & 1) ? X1 : X0;
        __bf16* Xq = (t & 1) ? X0 : X1;
        // D1: enc qkv (ehb_{t-1}) + dec qkv (dh_{t-1})
        gemm_qkv2<<<dim3(16,12), 256, 0, stream>>>(Xp, Wqkv_e, Wqkv_d,
                                                   q_e, kv_e, q_d, kv_d);
        // D2: enc attn + gates + LSTM -> ehb_t, ec
        f_enc<<<256, 512, 0, stream>>>(input, t, Xp, Xq, q_e, kv_e,
                                       Wg_e, encWg, encbg, ec);
        // D3: code + dec attn + gates + LSTM + outproj -> dh_t, outbuf
        f_dec<<<256, 512, 0, stream>>>(Xp, Xq, q_d, kv_d, WTemb, Wg_d,
                                       embb, decbg, outW, outbuf + t*Mz);
    }
    assemble_k<<<(Bz*(NSTEP-TPz)*Sz + 255)/256, 256, 0, stream>>>(
        outbuf, input, outb, (float*)d_out);
}